// Round 9
// baseline (395.789 us; speedup 1.0000x reference)
//
#include <hip/hip_runtime.h>
#include <hip/hip_bf16.h>

// B=4, N=4096, C=128, K=16. float32 in/out.
// R16: 318.5 (ref matvec map-C). R18: 320 (issue-count cuts: NEUTRAL).
// R19 (eig in mlp, 16-lane divergent): 351. R20 (eig 1pt/wave): 391.
// R21 (eig arrays in LDS, 1pt/thread): 315.1 -- eig ~55us; only ~4us gained
//      => eig is structurally capped: 16384 pts = 256 waves = 1 wave/CU as a
//      standalone kernel; NOTHING hides the QR dependent chain.
// R22: fuse eig into knn's EPILOGUE where 32 waves/CU are resident. Each knn
//      wave owns 2 points: lanes 0-15 stage nidx into wave-private LDS (same-
//      wave DS ordering, no barrier); lanes 0,1 run the 2 QRs (2-way union)
//      with R21-proven eig3_lds on wave-private slices of the dead tile4.
//      QR chains hide across the 32 resident waves. eig_kernel deleted.
//      Math verbatim (cov order, eig3_lds, nidx) -> bit-identical.
#define N_ 4096
#define C_ 128
#define K_ 16
#define NPT 16384
#define ESTR 19

__device__ __forceinline__ float wave_sum64(float v) {
#pragma unroll
  for (int off = 32; off >= 1; off >>= 1) v += __shfl_xor(v, off, 64);
  return v;
}

__device__ __forceinline__ float grp32_sum(float v) {
  v += __shfl_xor(v, 1, 64);
  v += __shfl_xor(v, 2, 64);
  v += __shfl_xor(v, 4, 64);
  v += __shfl_xor(v, 8, 64);
  v += __shfl_xor(v, 16, 64);
  return v;
}

// ---------------- LAPACK f32 helpers ----------------

__device__ __forceinline__ float sign_f(float a, float b) {
  return copysignf(fabsf(a), b);
}

__device__ float lapy2_f(float x, float y) {
#pragma clang fp contract(off)
  float xa = fabsf(x), ya = fabsf(y);
  float w = fmaxf(xa, ya), z = fminf(xa, ya);
  if (z == 0.0f) return w;
  float t = z / w;
  return w * sqrtf(1.0f + t * t);
}

__device__ void lartg_f(float f, float g, float& c, float& s, float& r) {
#pragma clang fp contract(off)
  if (g == 0.0f) {
    c = 1.0f; s = 0.0f; r = f;
  } else if (f == 0.0f) {
    c = 0.0f; s = copysignf(1.0f, g); r = fabsf(g);
  } else {
    float d = sqrtf(f * f + g * g);
    c = fabsf(f) / d;
    r = sign_f(d, f);
    s = g / r;
  }
}

__device__ void laev2_f(float a, float b, float cc, float& rt1, float& rt2,
                        float& cs1, float& sn1) {
#pragma clang fp contract(off)
  float sm = a + cc;
  float df = a - cc;
  float adf = fabsf(df);
  float tb = b + b;
  float ab = fabsf(tb);
  float acmx, acmn;
  if (fabsf(a) > fabsf(cc)) { acmx = a; acmn = cc; } else { acmx = cc; acmn = a; }
  float rt;
  if (adf > ab) {
    float t = ab / adf; rt = adf * sqrtf(1.0f + t * t);
  } else if (adf < ab) {
    float t = adf / ab; rt = ab * sqrtf(1.0f + t * t);
  } else {
    rt = ab * sqrtf(2.0f);
  }
  int sgn1;
  if (sm < 0.0f) {
    rt1 = 0.5f * (sm - rt); sgn1 = -1;
    rt2 = (acmx / rt1) * acmn - (b / rt1) * b;
  } else if (sm > 0.0f) {
    rt1 = 0.5f * (sm + rt); sgn1 = 1;
    rt2 = (acmx / rt1) * acmn - (b / rt1) * b;
  } else {
    rt1 = 0.5f * rt; rt2 = -0.5f * rt; sgn1 = 1;
  }
  float cs; int sgn2;
  if (df >= 0.0f) { cs = df + rt; sgn2 = 1; } else { cs = df - rt; sgn2 = -1; }
  float acs = fabsf(cs);
  if (acs > ab) {
    float ct = -tb / cs;
    sn1 = 1.0f / sqrtf(1.0f + ct * ct);
    cs1 = ct * sn1;
  } else {
    if (ab == 0.0f) { cs1 = 1.0f; sn1 = 0.0f; }
    else {
      float tn = -cs / tb;
      cs1 = 1.0f / sqrtf(1.0f + tn * tn);
      sn1 = tn * cs1;
    }
  }
  if (sgn1 == sgn2) { float tn = cs1; cs1 = -sn1; sn1 = tn; }
}

// LDS-backed variant (R21-proven): d[3], e[2], Z 3x3 row-major, csv[2], snv[2].
__device__ void steqr3_lds(float* __restrict__ d, float* __restrict__ e,
                           float* __restrict__ Z, float* __restrict__ csv,
                           float* __restrict__ snv) {
#pragma clang fp contract(off)
  const int n = 3;
  const float eps = 5.9604644775390625e-08f;
  const float eps2 = eps * eps;
  const float safmin = 1.17549435e-38f;
  const int nmaxit = n * 30;
  int jtot = 0;
  int l1 = 1;

  for (int og = 0; og < 16; ++og) {
    if (l1 > n) break;
    if (l1 > 1) e[l1 - 2] = 0.0f;
    int m, l, lend;
    if (l1 <= n - 1) {
      bool found = false;
      for (m = l1; m <= n - 1; ++m) {
        float tst = fabsf(e[m - 1]);
        if (tst == 0.0f) { found = true; break; }
        if (tst <= (sqrtf(fabsf(d[m - 1])) * sqrtf(fabsf(d[m]))) * eps) {
          e[m - 1] = 0.0f; found = true; break;
        }
      }
      if (!found) m = n;
    } else {
      m = n;
    }
    l = l1; lend = m; l1 = m + 1;
    if (lend == l) continue;
    if (fabsf(d[lend - 1]) < fabsf(d[l - 1])) { int t = l; l = lend; lend = t; }

    if (lend > l) {
      for (int it = 0; it < 128; ++it) {
        int mm;
        if (l != lend) {
          bool f2 = false;
          for (mm = l; mm <= lend - 1; ++mm) {
            float tst = e[mm - 1] * e[mm - 1];
            if (tst <= (eps2 * fabsf(d[mm - 1])) * fabsf(d[mm]) + safmin) { f2 = true; break; }
          }
          if (!f2) mm = lend;
        } else mm = lend;
        if (mm < lend) e[mm - 1] = 0.0f;
        float p = d[l - 1];
        if (mm == l) {
          d[l - 1] = p; ++l;
          if (l <= lend) continue;
          break;
        }
        if (mm == l + 1) {
          float rt1, rt2, cc, ss;
          laev2_f(d[l - 1], e[l - 1], d[l], rt1, rt2, cc, ss);
          for (int r = 0; r < n; ++r) {
            float temp = Z[r * 3 + l];
            Z[r * 3 + l] = cc * temp - ss * Z[r * 3 + l - 1];
            Z[r * 3 + l - 1] = ss * temp + cc * Z[r * 3 + l - 1];
          }
          d[l - 1] = rt1; d[l] = rt2; e[l - 1] = 0.0f;
          l += 2;
          if (l <= lend) continue;
          break;
        }
        if (jtot == nmaxit) break;
        ++jtot;
        float g = (d[l] - p) / (2.0f * e[l - 1]);
        float r = lapy2_f(g, 1.0f);
        g = d[mm - 1] - p + e[l - 1] / (g + sign_f(r, g));
        float s = 1.0f, c = 1.0f;
        p = 0.0f;
        for (int i = mm - 1; i >= l; --i) {
          float f = s * e[i - 1];
          float bb = c * e[i - 1];
          lartg_f(g, f, c, s, r);
          if (i != mm - 1) e[i] = r;
          g = d[i] - p;
          r = (d[i - 1] - g) * s + 2.0f * c * bb;
          p = s * r;
          d[i] = g + p;
          g = c * r - bb;
          csv[i - l] = c;
          snv[i - l] = -s;
        }
        int mml = mm - l;
        for (int j = mml; j >= 1; --j) {
          float cc = csv[j - 1], ss = snv[j - 1];
          for (int r2 = 0; r2 < n; ++r2) {
            float temp = Z[r2 * 3 + l + j - 1];
            Z[r2 * 3 + l + j - 1] = cc * temp - ss * Z[r2 * 3 + l + j - 2];
            Z[r2 * 3 + l + j - 2] = ss * temp + cc * Z[r2 * 3 + l + j - 2];
          }
        }
        d[l - 1] -= p;
        e[l - 1] = g;
      }
    } else {
      for (int it = 0; it < 128; ++it) {
        int mm;
        if (l != lend) {
          bool f2 = false;
          for (mm = l; mm >= lend + 1; --mm) {
            float tst = e[mm - 2] * e[mm - 2];
            if (tst <= (eps2 * fabsf(d[mm - 1])) * fabsf(d[mm - 2]) + safmin) { f2 = true; break; }
          }
          if (!f2) mm = lend;
        } else mm = lend;
        if (mm > lend) e[mm - 2] = 0.0f;
        float p = d[l - 1];
        if (mm == l) {
          d[l - 1] = p; --l;
          if (l >= lend) continue;
          break;
        }
        if (mm == l - 1) {
          float rt1, rt2, cc, ss;
          laev2_f(d[l - 2], e[l - 2], d[l - 1], rt1, rt2, cc, ss);
          for (int r = 0; r < n; ++r) {
            float temp = Z[r * 3 + l - 1];
            Z[r * 3 + l - 1] = cc * temp - ss * Z[r * 3 + l - 2];
            Z[r * 3 + l - 2] = ss * temp + cc * Z[r * 3 + l - 2];
          }
          d[l - 2] = rt1; d[l - 1] = rt2; e[l - 2] = 0.0f;
          l -= 2;
          if (l >= lend) continue;
          break;
        }
        if (jtot == nmaxit) break;
        ++jtot;
        float g = (d[l - 2] - p) / (2.0f * e[l - 2]);
        float r = lapy2_f(g, 1.0f);
        g = d[mm - 1] - p + e[l - 2] / (g + sign_f(r, g));
        float s = 1.0f, c = 1.0f;
        p = 0.0f;
        for (int i = mm; i <= l - 1; ++i) {
          float f = s * e[i - 1];
          float bb = c * e[i - 1];
          lartg_f(g, f, c, s, r);
          if (i != mm) e[i - 2] = r;
          g = d[i - 1] - p;
          r = (d[i] - g) * s + 2.0f * c * bb;
          p = s * r;
          d[i - 1] = g + p;
          g = c * r - bb;
          csv[i - mm] = c;
          snv[i - mm] = s;
        }
        int lm = l - mm;
        for (int j = 1; j <= lm; ++j) {
          float cc = csv[j - 1], ss = snv[j - 1];
          for (int r2 = 0; r2 < n; ++r2) {
            float temp = Z[r2 * 3 + mm + j - 1];
            Z[r2 * 3 + mm + j - 1] = cc * temp - ss * Z[r2 * 3 + mm + j - 2];
            Z[r2 * 3 + mm + j - 2] = ss * temp + cc * Z[r2 * 3 + mm + j - 2];
          }
        }
        d[l - 1] -= p;
        e[l - 2] = g;
      }
    }
  }
  for (int ii = 2; ii <= n; ++ii) {
    int i = ii - 1, k = i;
    float p = d[i - 1];
    for (int j = ii; j <= n; ++j) {
      if (d[j - 1] < p) { k = j; p = d[j - 1]; }
    }
    if (k != i) {
      d[k - 1] = d[i - 1]; d[i - 1] = p;
      for (int r = 0; r < n; ++r) {
        float t = Z[r * 3 + i - 1]; Z[r * 3 + i - 1] = Z[r * 3 + k - 1]; Z[r * 3 + k - 1] = t;
      }
    }
  }
}

// LDS-backed eig3 (R21-proven): layout d=+0(3), e=+3(2), Z=+5(9), csv=+14(2), snv=+16(2).
__device__ void eig3_lds(float A00, float A10, float A20,
                         float A11, float A21, float A22, float* __restrict__ base) {
#pragma clang fp contract(off)
  float* d = base;
  float* e = base + 3;
  float* Z = base + 5;
  float* csv = base + 14;
  float* snv = base + 16;
  float tau = 0.0f, v2 = 0.0f;
  d[0] = A00;
  float xnorm = fabsf(A20);
  if (xnorm == 0.0f) {
    tau = 0.0f; v2 = 0.0f;
    e[0] = A10; d[1] = A11; e[1] = A21; d[2] = A22;
  } else {
    float beta = -sign_f(lapy2_f(A10, xnorm), A10);
    tau = (beta - A10) / beta;
    float inv = 1.0f / (A10 - beta);
    v2 = A20 * inv;
    e[0] = beta;
    float x0 = tau * A11;
    float x1 = tau * A21;
    float tmp2 = A21 * v2;
    x0 = x0 + tau * tmp2;
    x1 = x1 + (tau * v2) * A22;
    float dotv = x0 + x1 * v2;
    float aw = (-0.5f * tau) * dotv;
    float w0 = x0 + aw;
    float w1 = x1 + aw * v2;
    d[1] = (A11 - w0) - w0;
    float pq = v2 * w0;
    e[1] = (A21 - pq) - w1;
    float pr = v2 * w1;
    d[2] = (A22 - pr) - pr;
  }
  Z[0] = 1.0f; Z[1] = 0.0f; Z[2] = 0.0f;
  Z[3] = 0.0f; Z[4] = 1.0f; Z[5] = 0.0f;
  Z[6] = 0.0f; Z[7] = 0.0f; Z[8] = 1.0f;
  steqr3_lds(d, e, Z, csv, snv);
  if (tau != 0.0f) {
    for (int j = 0; j < 3; ++j) {
      float sum = Z[3 + j] + v2 * Z[6 + j];
      float tw = tau * sum;
      Z[3 + j] = Z[3 + j] - tw;
      Z[6 + j] = Z[6 + j] - v2 * tw;
    }
  }
}

// Register-array variants kept for the fallback fused_kernel (proven path).
__device__ void steqr3_f(float d[3], float e[2], float Z[3][3]) {
#pragma clang fp contract(off)
  float csv[2], snv[2];
  steqr3_lds(d, e, &Z[0][0], csv, snv);
}

__device__ void eig3_f(float A00, float A10, float A20,
                       float A11, float A21, float A22, float Z[3][3]) {
#pragma clang fp contract(off)
  float d[3], e[2];
  float tau = 0.0f, v2 = 0.0f;
  d[0] = A00;
  float xnorm = fabsf(A20);
  if (xnorm == 0.0f) {
    tau = 0.0f; v2 = 0.0f;
    e[0] = A10; d[1] = A11; e[1] = A21; d[2] = A22;
  } else {
    float beta = -sign_f(lapy2_f(A10, xnorm), A10);
    tau = (beta - A10) / beta;
    float inv = 1.0f / (A10 - beta);
    v2 = A20 * inv;
    e[0] = beta;
    float x0 = tau * A11;
    float x1 = tau * A21;
    float tmp2 = A21 * v2;
    x0 = x0 + tau * tmp2;
    x1 = x1 + (tau * v2) * A22;
    float dotv = x0 + x1 * v2;
    float aw = (-0.5f * tau) * dotv;
    float w0 = x0 + aw;
    float w1 = x1 + aw * v2;
    d[1] = (A11 - w0) - w0;
    float pq = v2 * w0;
    e[1] = (A21 - pq) - w1;
    float pr = v2 * w1;
    d[2] = (A22 - pr) - pr;
  }
  Z[0][0] = 1.0f; Z[0][1] = 0.0f; Z[0][2] = 0.0f;
  Z[1][0] = 0.0f; Z[1][1] = 1.0f; Z[1][2] = 0.0f;
  Z[2][0] = 0.0f; Z[2][1] = 0.0f; Z[2][2] = 1.0f;
  steqr3_f(d, e, Z);
  if (tau != 0.0f) {
    for (int j = 0; j < 3; ++j) {
      float sum = Z[1][j] + v2 * Z[2][j];
      float tw = tau * sum;
      Z[1][j] = Z[1][j] - tw;
      Z[2][j] = Z[2][j] - v2 * tw;
    }
  }
}

// ---------------- KNN key (numpy-f32-faithful) ----------------
__device__ __forceinline__ unsigned long long knn_key(float qx, float qy, float qz,
                                                      float nqxx, float x, float y,
                                                      float z, int j) {
  const float dot = __fmaf_rn(qz, z, __fmaf_rn(qy, y, __fmul_rn(qx, x)));
  const float xxj =
      __fadd_rn(__fadd_rn(__fmul_rn(x, x), __fmul_rn(y, y)), __fmul_rn(z, z));
  const float inner = __fmul_rn(-2.0f, dot);
  const float pval = __fsub_rn(__fsub_rn(nqxx, inner), xxj);
  const unsigned bits = __float_as_uint(pval);
  const unsigned ordv = bits ^ (unsigned)(((int)bits >> 31) | 0x80000000);
  return ((unsigned long long)ordv << 32) | (unsigned)(4095 - j);
}

// ---------------- Kernel A: KNN + eig epilogue (R22) ----------------
__global__ __launch_bounds__(256, 6) void knn_kernel(const float* __restrict__ xyz,
                                                     int* __restrict__ nidx_ws,
                                                     float* __restrict__ gf_ws) {
  __shared__ float4 tile4[1024];   // (x,y,z,xx) per candidate; reused by epilogue

  const int wave = threadIdx.x >> 6;
  const int lane = threadIdx.x & 63;
  const int tid = threadIdx.x;
  const int P0 = blockIdx.x * 8;        // 8 points/block (2 per wave)
  const int b = P0 >> 12;
  const int r0 = P0 & 4095;
  const int pbase = r0 + wave * 2;
  const float* xb = xyz + (size_t)b * (N_ * 3);

  float qx[2], qy[2], qz[2], nqxx[2];
#pragma unroll
  for (int q = 0; q < 2; ++q) {
    const int i = pbase + q;
    qx[q] = xb[3 * i]; qy[q] = xb[3 * i + 1]; qz[q] = xb[3 * i + 2];
    nqxx[q] = -__fadd_rn(__fadd_rn(__fmul_rn(qx[q], qx[q]), __fmul_rn(qy[q], qy[q])),
                         __fmul_rn(qz[q], qz[q]));
  }

  unsigned long long pk[2][4];
#pragma unroll
  for (int q = 0; q < 2; ++q)
#pragma unroll
    for (int s = 0; s < 4; ++s) pk[q][s] = 0ull;

  for (int tile = 0; tile < 4; ++tile) {
    {
      const float4* gsrc = (const float4*)(xb + tile * 3072);
      float4 a0 = gsrc[tid * 3];
      float4 a1 = gsrc[tid * 3 + 1];
      float4 a2 = gsrc[tid * 3 + 2];
      const int base = tid * 4;
      const float xx0 = __fadd_rn(__fadd_rn(__fmul_rn(a0.x, a0.x), __fmul_rn(a0.y, a0.y)), __fmul_rn(a0.z, a0.z));
      const float xx1 = __fadd_rn(__fadd_rn(__fmul_rn(a0.w, a0.w), __fmul_rn(a1.x, a1.x)), __fmul_rn(a1.y, a1.y));
      const float xx2 = __fadd_rn(__fadd_rn(__fmul_rn(a1.z, a1.z), __fmul_rn(a1.w, a1.w)), __fmul_rn(a2.x, a2.x));
      const float xx3 = __fadd_rn(__fadd_rn(__fmul_rn(a2.y, a2.y), __fmul_rn(a2.z, a2.z)), __fmul_rn(a2.w, a2.w));
      tile4[base]     = make_float4(a0.x, a0.y, a0.z, xx0);
      tile4[base + 1] = make_float4(a0.w, a1.x, a1.y, xx1);
      tile4[base + 2] = make_float4(a1.z, a1.w, a2.x, xx2);
      tile4[base + 3] = make_float4(a2.y, a2.z, a2.w, xx3);
    }
    __syncthreads();

#pragma unroll 2
    for (int tloc = 0; tloc < 16; ++tloc) {
      const int idx = tloc * 64 + lane;
      const int j = tile * 1024 + idx;
      const float4 pv = tile4[idx];
      const float x = pv.x;
      const float y = pv.y;
      const float z = pv.z;
      const float xxj = pv.w;
      const unsigned jenc = (unsigned)(4095 - j);
#pragma unroll
      for (int q = 0; q < 2; ++q) {
        const float dot =
            __fmaf_rn(qz[q], z, __fmaf_rn(qy[q], y, __fmul_rn(qx[q], x)));
        const float inner = __fmul_rn(-2.0f, dot);
        const float pval = __fsub_rn(__fsub_rn(nqxx[q], inner), xxj);
        const unsigned bits = __float_as_uint(pval);
        const unsigned ordv = bits ^ (unsigned)(((int)bits >> 31) | 0x80000000);
        const unsigned long long key = ((unsigned long long)ordv << 32) | jenc;
        const bool c3 = key > pk[q][3];
        if (__any(c3)) {
          const bool c0 = key > pk[q][0], c1 = key > pk[q][1], c2 = key > pk[q][2];
          pk[q][3] = c3 ? (c2 ? pk[q][2] : key) : pk[q][3];
          pk[q][2] = c2 ? (c1 ? pk[q][1] : key) : pk[q][2];
          pk[q][1] = c1 ? (c0 ? pk[q][0] : key) : pk[q][1];
          pk[q][0] = c0 ? key : pk[q][0];
        }
      }
    }
    __syncthreads();
  }

  int stash[2];
  int h[2] = {0, 0};
#pragma unroll
  for (int k = 0; k < K_; ++k) {
    unsigned long long v[2];
#pragma unroll
    for (int q = 0; q < 2; ++q) v[q] = pk[q][0];
#pragma unroll
    for (int off = 32; off >= 1; off >>= 1) {
#pragma unroll
      for (int q = 0; q < 2; ++q) {
        unsigned long long ov = __shfl_xor(v[q], off, 64);
        if (ov > v[q]) v[q] = ov;
      }
    }
#pragma unroll
    for (int q = 0; q < 2; ++q) {
      const int jidx = (4095 - (int)(unsigned)(v[q] & 0xFFFFFFFFull)) & (N_ - 1);
      if (lane == k) stash[q] = jidx;
      if (pk[q][0] == v[q]) {
        pk[q][0] = pk[q][1]; pk[q][1] = pk[q][2]; pk[q][2] = pk[q][3];
        pk[q][3] = 0ull;
        ++h[q];
      }
    }
  }
#pragma unroll
  for (int q = 0; q < 2; ++q) {
    if (__ballot(h[q] >= 4) != 0ull) {
      unsigned long long qq[K_];
#pragma unroll
      for (int k = 0; k < K_; ++k) qq[k] = 0ull;
      for (int t = 0; t < 64; ++t) {
        const int j = t * 64 + lane;
        const unsigned long long key = knn_key(qx[q], qy[q], qz[q], nqxx[q],
                                               xb[3 * j], xb[3 * j + 1],
                                               xb[3 * j + 2], j);
        bool c[K_];
#pragma unroll
        for (int s = 0; s < K_; ++s) c[s] = key > qq[s];
#pragma unroll
        for (int s = K_ - 1; s >= 1; --s)
          qq[s] = c[s] ? (c[s - 1] ? qq[s - 1] : key) : qq[s];
        qq[0] = c[0] ? key : qq[0];
      }
#pragma unroll
      for (int k = 0; k < K_; ++k) {
        unsigned long long v = qq[0];
#pragma unroll
        for (int off = 32; off >= 1; off >>= 1) {
          unsigned long long ov = __shfl_xor(v, off, 64);
          if (ov > v) v = ov;
        }
        const int jidx = (4095 - (int)(unsigned)(v & 0xFFFFFFFFull)) & (N_ - 1);
        if (lane == k) stash[q] = jidx;
        if (qq[0] == v) {
#pragma unroll
          for (int s = 0; s < K_ - 1; ++s) qq[s] = qq[s + 1];
          qq[K_ - 1] = 0ull;
        }
      }
    }
  }

  if (lane < K_) {
    const int pg = P0 + wave * 2;
#pragma unroll
    for (int q = 0; q < 2; ++q)
      nidx_ws[(size_t)(pg + q) * K_ + lane] = stash[q];
  }

  // ---- R22 eig epilogue: wave-private; no cross-wave sync needed.
  // tile4 is dead after the last __syncthreads (fallback reads global only).
  // Layout: ints nls[8*16] at tile4 base; float QR slices at +1024 floats.
  {
    int* nls = (int*)tile4;                         // 8 pts x 16 ints
    float* ew = ((float*)tile4) + 1024;             // 8 x ESTR floats
    if (lane < K_) {
      nls[(wave * 2 + 0) * K_ + lane] = stash[0];
      nls[(wave * 2 + 1) * K_ + lane] = stash[1];
    }
    // same-wave DS program order: writes above complete before reads below
    if (lane < 2) {
      const int q = lane;
      const int p = P0 + wave * 2 + q;
      const float qx0 = (q == 0) ? qx[0] : qx[1];
      const float qy0 = (q == 0) ? qy[0] : qy[1];
      const float qz0 = (q == 0) ? qz[0] : qz[1];
      const int* nj = nls + (wave * 2 + q) * K_;

      float c00 = 0, c01 = 0, c02 = 0, c11 = 0, c12 = 0, c22 = 0;
      float mrx = 0, mry = 0, mrz = 0, md = 0;
#pragma unroll
      for (int k = 0; k < K_; ++k) {
        const int j = nj[k];
        const float rx = __fsub_rn(xb[3 * j], qx0);
        const float ry = __fsub_rn(xb[3 * j + 1], qy0);
        const float rz = __fsub_rn(xb[3 * j + 2], qz0);
        c00 = __fadd_rn(c00, __fmul_rn(rx, rx));
        c01 = __fadd_rn(c01, __fmul_rn(rx, ry));
        c02 = __fadd_rn(c02, __fmul_rn(rx, rz));
        c11 = __fadd_rn(c11, __fmul_rn(ry, ry));
        c12 = __fadd_rn(c12, __fmul_rn(ry, rz));
        c22 = __fadd_rn(c22, __fmul_rn(rz, rz));
        mrx = __fadd_rn(mrx, rx);
        mry = __fadd_rn(mry, ry);
        mrz = __fadd_rn(mrz, rz);
        const float nn = __fadd_rn(__fadd_rn(__fmul_rn(rx, rx), __fmul_rn(ry, ry)),
                                   __fmul_rn(rz, rz));
        md = __fadd_rn(md, sqrtf(nn));
      }
      const float s16 = 0.0625f;
      float* base = ew + (wave * 2 + q) * ESTR;
      eig3_lds(__fmul_rn(c00, s16), __fmul_rn(c01, s16), __fmul_rn(c02, s16),
               __fmul_rn(c11, s16), __fmul_rn(c12, s16), __fmul_rn(c22, s16), base);
      const float* Z = base + 5;   // row-major 3x3
      float* g = gf_ws + (size_t)p * 12;
      g[0] = Z[0]; g[1] = Z[3]; g[2] = Z[6];    // eigvec col 0 (normal)
      g[3] = Z[2]; g[4] = Z[5]; g[5] = Z[8];    // eigvec col 2 (curvature)
      g[6] = __fmul_rn(mrx, s16); g[7] = __fmul_rn(mry, s16);
      g[8] = __fmul_rn(mrz, s16);
      g[9] = __fmul_rn(md, s16);
    }
  }
}

// ---------------- Kernel B: block-cooperative MLPs (R16 + R18, proven) ----------------
__global__ __launch_bounds__(256) void mlp_kernel(
    const float* __restrict__ feats, const int* __restrict__ nidx_ws,
    const float* __restrict__ gf_ws,
    const float* __restrict__ geo_w1, const float* __restrict__ geo_b1,
    const float* __restrict__ geo_g1, const float* __restrict__ geo_be1,
    const float* __restrict__ geo_w2, const float* __restrict__ geo_b2,
    const float* __restrict__ diff_w1, const float* __restrict__ diff_b1,
    const float* __restrict__ diff_g1, const float* __restrict__ diff_be1,
    const float* __restrict__ diff_w2, const float* __restrict__ diff_b2,
    const float* __restrict__ ep_w1, const float* __restrict__ ep_b1,
    const float* __restrict__ ep_w2, const float* __restrict__ ep_b2,
    const float* __restrict__ ref_w1, const float* __restrict__ ref_b1,
    const float* __restrict__ ref_g1, const float* __restrict__ ref_be1,
    float* __restrict__ out, float* __restrict__ out_prob) {

  __shared__ float w[8192];
  __shared__ float fsh[16 * 128];
  __shared__ float sdif[16 * 128];
  __shared__ float ysh[16 * 64];
  __shared__ float edsh[16 * 128];
  __shared__ float insh[16 * 12];
  __shared__ int nsh[16 * 16];

  const int tid = threadIdx.x;
  const int lane = tid & 63;
  const int g = tid >> 6;
  const int P0 = blockIdx.x * 16;
  const int b = P0 >> 12;
  const int r0 = P0 & 4095;
  const float* fb = feats + (size_t)b * N_ * C_;

  if (tid < 192) insh[tid] = gf_ws[(size_t)P0 * 12 + tid];
  nsh[tid] = nidx_ws[(size_t)P0 * K_ + tid];
#pragma unroll
  for (int m = 0; m < 8; ++m)
    fsh[m * 256 + tid] = fb[(size_t)r0 * C_ + m * 256 + tid];
  if (tid < 160) ((float4*)w)[tid] = ((const float4*)geo_w1)[tid];
#pragma unroll
  for (int m = 0; m < 4; ++m)
    ((float4*)(w + 640))[m * 256 + tid] = ((const float4*)geo_w2)[m * 256 + tid];
  __syncthreads();

  // geo layer 1 (channel-outer, R12 unchanged) + LN
  {
    float acc[4] = {0, 0, 0, 0};
#pragma unroll
    for (int c = 0; c < 10; ++c) {
      const float wv = w[c * 64 + lane];
#pragma unroll
      for (int ptl = 0; ptl < 4; ++ptl)
        acc[ptl] += insh[(g * 4 + ptl) * 12 + c] * wv;
    }
#pragma unroll
    for (int ptl = 0; ptl < 4; ++ptl) {
      const int pt = g * 4 + ptl;
      float a = acc[ptl] + geo_b1[lane];
      float m = wave_sum64(a) * (1.0f / 64.0f);
      float xm = a - m;
      float var = wave_sum64(xm * xm) * (1.0f / 64.0f);
      float yv = xm * (1.0f / sqrtf(var + 1e-5f)) * geo_g1[lane] + geo_be1[lane];
      ysh[pt * 64 + lane] = fmaxf(yv, 0.0f);
    }
  }
  __syncthreads();

  // geo layer 2: R12 weights + float4 activation broadcasts (R18)
  float ge[4] = {0, 0, 0, 0}, de[4], prob[4];
#pragma unroll 2
  for (int c4 = 0; c4 < 64; c4 += 4) {
    const float w0 = w[640 + (c4 + 0) * 64 + lane];
    const float w1 = w[640 + (c4 + 1) * 64 + lane];
    const float w2 = w[640 + (c4 + 2) * 64 + lane];
    const float w3 = w[640 + (c4 + 3) * 64 + lane];
#pragma unroll
    for (int ptl = 0; ptl < 4; ++ptl) {
      const float4 yv = *(const float4*)(ysh + (g * 4 + ptl) * 64 + c4);
      ge[ptl] += yv.x * w0; ge[ptl] += yv.y * w1;
      ge[ptl] += yv.z * w2; ge[ptl] += yv.w * w3;
    }
  }
#pragma unroll
  for (int ptl = 0; ptl < 4; ++ptl) ge[ptl] += geo_b2[lane];

  // feat_diff: float4 gathers (R17-proven); 8 groups of 32 threads, 2 points each.
  {
    const int grp = tid >> 5;
    const int c4 = (tid & 31) * 4;
#pragma unroll
    for (int pp = 0; pp < 2; ++pp) {
      const int pt = grp * 2 + pp;
      const float4 fv = *(const float4*)(fsh + pt * 128 + c4);
      float s0 = 0, s1 = 0, s2 = 0, s3 = 0;
      for (int k = 0; k < K_; ++k) {
        const int j = nsh[pt * 16 + k];
        const float4 a = *(const float4*)(fb + (size_t)j * C_ + c4);
        s0 += fabsf(fv.x - a.x);
        s1 += fabsf(fv.y - a.y);
        s2 += fabsf(fv.z - a.z);
        s3 += fabsf(fv.w - a.w);
      }
      const float sc = 1.0f / 16.0f;
      *(float4*)(sdif + pt * 128 + c4) =
          make_float4(s0 * sc, s1 * sc, s2 * sc, s3 * sc);
    }
  }
  __syncthreads();
#pragma unroll
  for (int m = 0; m < 8; ++m)
    ((float4*)w)[m * 256 + tid] = ((const float4*)diff_w1)[m * 256 + tid];
  __syncthreads();

  // diff layer 1: R12 weights + float4 activation broadcasts + LN (R12 LN)
  {
    float acc[4] = {0, 0, 0, 0};
#pragma unroll 2
    for (int c4 = 0; c4 < 128; c4 += 4) {
      const float w0 = w[(c4 + 0) * 64 + lane];
      const float w1 = w[(c4 + 1) * 64 + lane];
      const float w2 = w[(c4 + 2) * 64 + lane];
      const float w3 = w[(c4 + 3) * 64 + lane];
#pragma unroll
      for (int ptl = 0; ptl < 4; ++ptl) {
        const float4 sv = *(const float4*)(sdif + (g * 4 + ptl) * 128 + c4);
        acc[ptl] += sv.x * w0; acc[ptl] += sv.y * w1;
        acc[ptl] += sv.z * w2; acc[ptl] += sv.w * w3;
      }
    }
#pragma unroll
    for (int ptl = 0; ptl < 4; ++ptl) {
      const int pt = g * 4 + ptl;
      float a = acc[ptl] + diff_b1[lane];
      float m = wave_sum64(a) * (1.0f / 64.0f);
      float xm = a - m;
      float var = wave_sum64(xm * xm) * (1.0f / 64.0f);
      float yv = xm * (1.0f / sqrtf(var + 1e-5f)) * diff_g1[lane] + diff_be1[lane];
      ysh[pt * 64 + lane] = fmaxf(yv, 0.0f);
    }
  }
  __syncthreads();
#pragma unroll
  for (int m = 0; m < 4; ++m)
    ((float4*)w)[m * 256 + tid] = ((const float4*)diff_w2)[m * 256 + tid];
#pragma unroll
  for (int m = 0; m < 4; ++m)
    ((float4*)w)[1024 + m * 256 + tid] = ((const float4*)ep_w1)[m * 256 + tid];
  __syncthreads();

  // diff layer 2: R12 weights + float4 activations, stash [ge||de]
  {
    float acc[4] = {0, 0, 0, 0};
#pragma unroll 2
    for (int c4 = 0; c4 < 64; c4 += 4) {
      const float w0 = w[(c4 + 0) * 64 + lane];
      const float w1 = w[(c4 + 1) * 64 + lane];
      const float w2 = w[(c4 + 2) * 64 + lane];
      const float w3 = w[(c4 + 3) * 64 + lane];
#pragma unroll
      for (int ptl = 0; ptl < 4; ++ptl) {
        const float4 yv = *(const float4*)(ysh + (g * 4 + ptl) * 64 + c4);
        acc[ptl] += yv.x * w0; acc[ptl] += yv.y * w1;
        acc[ptl] += yv.z * w2; acc[ptl] += yv.w * w3;
      }
    }
#pragma unroll
    for (int ptl = 0; ptl < 4; ++ptl) {
      const int pt = g * 4 + ptl;
      de[ptl] = acc[ptl] + diff_b2[lane];
      edsh[pt * 128 + lane] = ge[ptl];
      edsh[pt * 128 + 64 + lane] = de[ptl];
    }
  }
  __syncthreads();

  // edge-prob MLP: R12 weights + float4 activations; reduction/sigmoid R12
  const int u = lane & 31;
  {
    float ea[4] = {0, 0, 0, 0};
#pragma unroll 2
    for (int c4 = 0; c4 < 128; c4 += 4) {
      const float w0 = w[4096 + (c4 + 0) * 32 + u];
      const float w1 = w[4096 + (c4 + 1) * 32 + u];
      const float w2 = w[4096 + (c4 + 2) * 32 + u];
      const float w3 = w[4096 + (c4 + 3) * 32 + u];
#pragma unroll
      for (int ptl = 0; ptl < 4; ++ptl) {
        const float4 ev = *(const float4*)(edsh + (g * 4 + ptl) * 128 + c4);
        ea[ptl] += ev.x * w0; ea[ptl] += ev.y * w1;
        ea[ptl] += ev.z * w2; ea[ptl] += ev.w * w3;
      }
    }
#pragma unroll
    for (int ptl = 0; ptl < 4; ++ptl) {
      float a = ea[ptl] + ep_b1[u];
      float hh = (lane < 32) ? fmaxf(a, 0.0f) * ep_w2[u] : 0.0f;
      float tsum = wave_sum64(hh) + ep_b2[0];
      prob[ptl] = 1.0f / (1.0f + expf(-tsum));
      if (lane == 0) out_prob[P0 + g * 4 + ptl] = prob[ptl];
    }
  }
  __syncthreads();
#pragma unroll
  for (int ptl = 0; ptl < 4; ++ptl) {
    const int pt = g * 4 + ptl;
    edsh[pt * 128 + lane] = ge[ptl] * prob[ptl];
    edsh[pt * 128 + 64 + lane] = de[ptl] * prob[ptl];
  }

  // ---- ref matvec (R16 map C, proven): thread -> (ptA,ptB, 4 consecutive out-ch) ----
  const int p2 = tid >> 5;
  const int ptA = p2 * 2, ptB = ptA + 1;
  const int oc4 = (tid & 31) * 4;
  float A0 = 0, A1 = 0, A2 = 0, A3 = 0;
  float B0 = 0, B1 = 0, B2 = 0, B3 = 0;
  for (int ch = 0; ch < 4; ++ch) {
    __syncthreads();
    {
      const float4* gsrc = (const float4*)(ref_w1 + ch * 8192);
#pragma unroll
      for (int m = 0; m < 8; ++m) ((float4*)w)[m * 256 + tid] = gsrc[m * 256 + tid];
    }
    __syncthreads();
    const float* eA = (ch < 2) ? (fsh + ptA * 128 + ch * 64)
                               : (edsh + ptA * 128 + (ch - 2) * 64);
    const float* eB = (ch < 2) ? (fsh + ptB * 128 + ch * 64)
                               : (edsh + ptB * 128 + (ch - 2) * 64);
#pragma unroll 4
    for (int c4 = 0; c4 < 64; c4 += 4) {
      const float4 ea = *(const float4*)(eA + c4);
      const float4 eb = *(const float4*)(eB + c4);
      const float4 w0 = *(const float4*)(w + (c4 + 0) * 128 + oc4);
      const float4 w1 = *(const float4*)(w + (c4 + 1) * 128 + oc4);
      const float4 w2 = *(const float4*)(w + (c4 + 2) * 128 + oc4);
      const float4 w3 = *(const float4*)(w + (c4 + 3) * 128 + oc4);
      A0 += ea.x * w0.x; A0 += ea.y * w1.x; A0 += ea.z * w2.x; A0 += ea.w * w3.x;
      A1 += ea.x * w0.y; A1 += ea.y * w1.y; A1 += ea.z * w2.y; A1 += ea.w * w3.y;
      A2 += ea.x * w0.z; A2 += ea.y * w1.z; A2 += ea.z * w2.z; A2 += ea.w * w3.z;
      A3 += ea.x * w0.w; A3 += ea.y * w1.w; A3 += ea.z * w2.w; A3 += ea.w * w3.w;
      B0 += eb.x * w0.x; B0 += eb.y * w1.x; B0 += eb.z * w2.x; B0 += eb.w * w3.x;
      B1 += eb.x * w0.y; B1 += eb.y * w1.y; B1 += eb.z * w2.y; B1 += eb.w * w3.y;
      B2 += eb.x * w0.z; B2 += eb.y * w1.z; B2 += eb.z * w2.z; B2 += eb.w * w3.z;
      B3 += eb.x * w0.w; B3 += eb.y * w1.w; B3 += eb.z * w2.w; B3 += eb.w * w3.w;
    }
  }

  // ---- epilogue (map C): LN over 128 ch = 32 lanes x 4, relu, residual ----
  {
    const float4 rb = *(const float4*)(ref_b1 + oc4);
    A0 += rb.x; A1 += rb.y; A2 += rb.z; A3 += rb.w;
    B0 += rb.x; B1 += rb.y; B2 += rb.z; B3 += rb.w;
    const float4 gg = *(const float4*)(ref_g1 + oc4);
    const float4 be = *(const float4*)(ref_be1 + oc4);

    const float mA = grp32_sum(A0 + A1 + A2 + A3) * (1.0f / 128.0f);
    const float dA0 = A0 - mA, dA1 = A1 - mA, dA2 = A2 - mA, dA3 = A3 - mA;
    const float vA =
        grp32_sum(dA0 * dA0 + dA1 * dA1 + dA2 * dA2 + dA3 * dA3) * (1.0f / 128.0f);
    const float rsA = 1.0f / sqrtf(vA + 1e-5f);
    const float4 resA = *(const float4*)(fsh + ptA * 128 + oc4);
    float4 yA;
    yA.x = fmaxf(dA0 * rsA * gg.x + be.x, 0.0f) + resA.x;
    yA.y = fmaxf(dA1 * rsA * gg.y + be.y, 0.0f) + resA.y;
    yA.z = fmaxf(dA2 * rsA * gg.z + be.z, 0.0f) + resA.z;
    yA.w = fmaxf(dA3 * rsA * gg.w + be.w, 0.0f) + resA.w;
    *(float4*)(out + (size_t)(P0 + ptA) * 128 + oc4) = yA;

    const float mB = grp32_sum(B0 + B1 + B2 + B3) * (1.0f / 128.0f);
    const float dB0 = B0 - mB, dB1 = B1 - mB, dB2 = B2 - mB, dB3 = B3 - mB;
    const float vB =
        grp32_sum(dB0 * dB0 + dB1 * dB1 + dB2 * dB2 + dB3 * dB3) * (1.0f / 128.0f);
    const float rsB = 1.0f / sqrtf(vB + 1e-5f);
    const float4 resB = *(const float4*)(fsh + ptB * 128 + oc4);
    float4 yB;
    yB.x = fmaxf(dB0 * rsB * gg.x + be.x, 0.0f) + resB.x;
    yB.y = fmaxf(dB1 * rsB * gg.y + be.y, 0.0f) + resB.y;
    yB.z = fmaxf(dB2 * rsB * gg.z + be.z, 0.0f) + resB.z;
    yB.w = fmaxf(dB3 * rsB * gg.w + be.w, 0.0f) + resB.w;
    *(float4*)(out + (size_t)(P0 + ptB) * 128 + oc4) = yB;
  }
}

// ---------------- Fallback: R8 fused kernel (proven) ----------------
__global__ __launch_bounds__(256) void fused_kernel(
    const float* __restrict__ xyz, const float* __restrict__ feats,
    const float* __restrict__ geo_w1, const float* __restrict__ geo_b1,
    const float* __restrict__ geo_g1, const float* __restrict__ geo_be1,
    const float* __restrict__ geo_w2, const float* __restrict__ geo_b2,
    const float* __restrict__ diff_w1, const float* __restrict__ diff_b1,
    const float* __restrict__ diff_g1, const float* __restrict__ diff_be1,
    const float* __restrict__ diff_w2, const float* __restrict__ diff_b2,
    const float* __restrict__ ep_w1, const float* __restrict__ ep_b1,
    const float* __restrict__ ep_w2, const float* __restrict__ ep_b2,
    const float* __restrict__ ref_w1, const float* __restrict__ ref_b1,
    const float* __restrict__ ref_g1, const float* __restrict__ ref_be1,
    float* __restrict__ out, float* __restrict__ out_prob) {

  __shared__ float4 tile4[1024];

  const int wave = threadIdx.x >> 6;
  const int lane = threadIdx.x & 63;
  const int tid = threadIdx.x;
  const int p = blockIdx.x * 4 + wave;
  const int b = p >> 12;
  const int i = p & 4095;
  const float* xb = xyz + (size_t)b * (N_ * 3);

  const float qx = xb[3 * i];
  const float qy = xb[3 * i + 1];
  const float qz = xb[3 * i + 2];
  const float qxx =
      __fadd_rn(__fadd_rn(__fmul_rn(qx, qx), __fmul_rn(qy, qy)), __fmul_rn(qz, qz));
  const float nqxx = -qxx;

  unsigned long long pk[4] = {0ull, 0ull, 0ull, 0ull};
  for (int tile = 0; tile < 4; ++tile) {
    {
      const float4* gsrc = (const float4*)(xb + tile * 3072);
      float4 r0v = gsrc[tid * 3];
      float4 r1 = gsrc[tid * 3 + 1];
      float4 r2 = gsrc[tid * 3 + 2];
      const int base = tid * 4;
      tile4[base]     = make_float4(r0v.x, r0v.y, r0v.z, 0.0f);
      tile4[base + 1] = make_float4(r0v.w, r1.x, r1.y, 0.0f);
      tile4[base + 2] = make_float4(r1.z, r1.w, r2.x, 0.0f);
      tile4[base + 3] = make_float4(r2.y, r2.z, r2.w, 0.0f);
    }
    __syncthreads();
#pragma unroll 4
    for (int tloc = 0; tloc < 16; ++tloc) {
      const int j = tile * 1024 + tloc * 64 + lane;
      const float4 pt = tile4[tloc * 64 + lane];
      const unsigned long long key = knn_key(qx, qy, qz, nqxx, pt.x, pt.y, pt.z, j);
      const bool c0 = key > pk[0], c1 = key > pk[1], c2 = key > pk[2], c3 = key > pk[3];
      pk[3] = c3 ? (c2 ? pk[2] : key) : pk[3];
      pk[2] = c2 ? (c1 ? pk[1] : key) : pk[2];
      pk[1] = c1 ? (c0 ? pk[0] : key) : pk[1];
      pk[0] = c0 ? key : pk[0];
    }
    __syncthreads();
  }

  int nidx[K_];
  int h = 0;
#pragma unroll
  for (int k = 0; k < K_; ++k) {
    unsigned long long v = pk[0];
#pragma unroll
    for (int off = 32; off >= 1; off >>= 1) {
      unsigned long long ov = __shfl_xor(v, off, 64);
      if (ov > v) v = ov;
    }
    nidx[k] = (4095 - (int)(unsigned)(v & 0xFFFFFFFFull)) & (N_ - 1);
    if (pk[0] == v) {
      pk[0] = pk[1]; pk[1] = pk[2]; pk[2] = pk[3]; pk[3] = 0ull;
      ++h;
    }
  }
  if (__ballot(h >= 4) != 0ull) {
    unsigned long long q[K_];
#pragma unroll
    for (int k = 0; k < K_; ++k) q[k] = 0ull;
    for (int t = 0; t < 64; ++t) {
      const int j = t * 64 + lane;
      const unsigned long long key =
          knn_key(qx, qy, qz, nqxx, xb[3 * j], xb[3 * j + 1], xb[3 * j + 2], j);
      bool c[K_];
#pragma unroll
      for (int s = 0; s < K_; ++s) c[s] = key > q[s];
#pragma unroll
      for (int s = K_ - 1; s >= 1; --s)
        q[s] = c[s] ? (c[s - 1] ? q[s - 1] : key) : q[s];
      q[0] = c[0] ? key : q[0];
    }
#pragma unroll
    for (int k = 0; k < K_; ++k) {
      unsigned long long v = q[0];
#pragma unroll
      for (int off = 32; off >= 1; off >>= 1) {
        unsigned long long ov = __shfl_xor(v, off, 64);
        if (ov > v) v = ov;
      }
      nidx[k] = (4095 - (int)(unsigned)(v & 0xFFFFFFFFull)) & (N_ - 1);
      if (q[0] == v) {
#pragma unroll
        for (int s = 0; s < K_ - 1; ++s) q[s] = q[s + 1];
        q[K_ - 1] = 0ull;
      }
    }
  }

  float c00 = 0, c01 = 0, c02 = 0, c11 = 0, c12 = 0, c22 = 0;
  float mrx = 0, mry = 0, mrz = 0, md = 0;
#pragma unroll
  for (int k = 0; k < K_; ++k) {
    const int j = nidx[k];
    const float rx = __fsub_rn(xb[3 * j], qx);
    const float ry = __fsub_rn(xb[3 * j + 1], qy);
    const float rz = __fsub_rn(xb[3 * j + 2], qz);
    c00 = __fadd_rn(c00, __fmul_rn(rx, rx));
    c01 = __fadd_rn(c01, __fmul_rn(rx, ry));
    c02 = __fadd_rn(c02, __fmul_rn(rx, rz));
    c11 = __fadd_rn(c11, __fmul_rn(ry, ry));
    c12 = __fadd_rn(c12, __fmul_rn(ry, rz));
    c22 = __fadd_rn(c22, __fmul_rn(rz, rz));
    mrx = __fadd_rn(mrx, rx);
    mry = __fadd_rn(mry, ry);
    mrz = __fadd_rn(mrz, rz);
    const float nn = __fadd_rn(__fadd_rn(__fmul_rn(rx, rx), __fmul_rn(ry, ry)),
                               __fmul_rn(rz, rz));
    md = __fadd_rn(md, sqrtf(nn));
  }
  const float s16 = 0.0625f;
  float Z[3][3];
  eig3_f(__fmul_rn(c00, s16), __fmul_rn(c01, s16), __fmul_rn(c02, s16),
         __fmul_rn(c11, s16), __fmul_rn(c12, s16), __fmul_rn(c22, s16), Z);
  float gf[10];
  gf[0] = Z[0][0]; gf[1] = Z[1][0]; gf[2] = Z[2][0];
  gf[3] = Z[0][2]; gf[4] = Z[1][2]; gf[5] = Z[2][2];
  gf[6] = __fmul_rn(mrx, s16); gf[7] = __fmul_rn(mry, s16);
  gf[8] = __fmul_rn(mrz, s16);
  gf[9] = __fmul_rn(md, s16);

  float acc = 0.0f;
#pragma unroll
  for (int ii = 0; ii < 10; ++ii) acc += gf[ii] * geo_w1[ii * 64 + lane];
  acc += geo_b1[lane];
  float yr;
  {
    float m = wave_sum64(acc) * (1.0f / 64.0f);
    float xm = acc - m;
    float var = wave_sum64(xm * xm) * (1.0f / 64.0f);
    float yv = xm * (1.0f / sqrtf(var + 1e-5f)) * geo_g1[lane] + geo_be1[lane];
    yr = fmaxf(yv, 0.0f);
  }
  float ge = 0.0f;
#pragma unroll 8
  for (int jj = 0; jj < 64; ++jj) ge += __shfl(yr, jj, 64) * geo_w2[jj * 64 + lane];
  ge += geo_b2[lane];

  const float* fb = feats + (size_t)b * N_ * C_;
  const float* fi = fb + (size_t)i * C_;
  const float f0 = fi[lane];
  const float f1 = fi[64 + lane];
  float s0 = 0.0f, s1 = 0.0f;
#pragma unroll
  for (int k = 0; k < K_; ++k) {
    const float* fj = fb + (size_t)nidx[k] * C_;
    s0 += fabsf(f0 - fj[lane]);
    s1 += fabsf(f1 - fj[64 + lane]);
  }
  s0 *= (1.0f / 16.0f);
  s1 *= (1.0f / 16.0f);
  float acc2 = 0.0f;
#pragma unroll 8
  for (int c = 0; c < 64; ++c) acc2 += __shfl(s0, c, 64) * diff_w1[c * 64 + lane];
#pragma unroll 8
  for (int c = 64; c < 128; ++c) acc2 += __shfl(s1, c - 64, 64) * diff_w1[c * 64 + lane];
  acc2 += diff_b1[lane];
  float yr2;
  {
    float m = wave_sum64(acc2) * (1.0f / 64.0f);
    float xm = acc2 - m;
    float var = wave_sum64(xm * xm) * (1.0f / 64.0f);
    float yv = xm * (1.0f / sqrtf(var + 1e-5f)) * diff_g1[lane] + diff_be1[lane];
    yr2 = fmaxf(yv, 0.0f);
  }
  float de = 0.0f;
#pragma unroll 8
  for (int jj = 0; jj < 64; ++jj) de += __shfl(yr2, jj, 64) * diff_w2[jj * 64 + lane];
  de += diff_b2[lane];

  {
    const int u = lane & 31;
    float a = 0.0f;
#pragma unroll 8
    for (int c = 0; c < 64; ++c) a += __shfl(ge, c, 64) * ep_w1[c * 32 + u];
#pragma unroll 8
    for (int c = 64; c < 128; ++c) a += __shfl(de, c - 64, 64) * ep_w1[c * 32 + u];
    a += ep_b1[u];
    float hh = (lane < 32) ? fmaxf(a, 0.0f) * ep_w2[u] : 0.0f;
    float tsum = wave_sum64(hh) + ep_b2[0];
    float prob = 1.0f / (1.0f + expf(-tsum));

    const float gep = ge * prob;
    const float dep = de * prob;
    float a0 = 0.0f, a1 = 0.0f;
#pragma unroll 4
    for (int c = 0; c < 64; ++c) {
      float ec = __shfl(f0, c, 64);
      a0 += ec * ref_w1[c * 128 + lane];
      a1 += ec * ref_w1[c * 128 + 64 + lane];
    }
#pragma unroll 4
    for (int c = 64; c < 128; ++c) {
      float ec = __shfl(f1, c - 64, 64);
      a0 += ec * ref_w1[c * 128 + lane];
      a1 += ec * ref_w1[c * 128 + 64 + lane];
    }
#pragma unroll 4
    for (int c = 128; c < 192; ++c) {
      float ec = __shfl(gep, c - 128, 64);
      a0 += ec * ref_w1[c * 128 + lane];
      a1 += ec * ref_w1[c * 128 + 64 + lane];
    }
#pragma unroll 4
    for (int c = 192; c < 256; ++c) {
      float ec = __shfl(dep, c - 192, 64);
      a0 += ec * ref_w1[c * 128 + lane];
      a1 += ec * ref_w1[c * 128 + 64 + lane];
    }
    a0 += ref_b1[lane];
    a1 += ref_b1[64 + lane];
    float mm2 = wave_sum64(a0 + a1) * (1.0f / 128.0f);
    float d0 = a0 - mm2, d1 = a1 - mm2;
    float var2 = wave_sum64(d0 * d0 + d1 * d1) * (1.0f / 128.0f);
    float rs = 1.0f / sqrtf(var2 + 1e-5f);
    float y0 = d0 * rs * ref_g1[lane] + ref_be1[lane];
    float y1 = d1 * rs * ref_g1[64 + lane] + ref_be1[64 + lane];
    y0 = fmaxf(y0, 0.0f) + f0;
    y1 = fmaxf(y1, 0.0f) + f1;
    out[(size_t)p * 128 + lane] = y0;
    out[(size_t)p * 128 + 64 + lane] = y1;
    if (lane == 0) out_prob[p] = prob;
  }
}

extern "C" void kernel_launch(void* const* d_in, const int* in_sizes, int n_in,
                              void* d_out, int out_size, void* d_ws, size_t ws_size,
                              hipStream_t stream) {
  const float* xyz = (const float*)d_in[0];
  const float* features = (const float*)d_in[1];
  const float* geo_w1 = (const float*)d_in[2];
  const float* geo_b1 = (const float*)d_in[3];
  const float* geo_g1 = (const float*)d_in[4];
  const float* geo_be1 = (const float*)d_in[5];
  const float* geo_w2 = (const float*)d_in[6];
  const float* geo_b2 = (const float*)d_in[7];
  const float* diff_w1 = (const float*)d_in[8];
  const float* diff_b1 = (const float*)d_in[9];
  const float* diff_g1 = (const float*)d_in[10];
  const float* diff_be1 = (const float*)d_in[11];
  const float* diff_w2 = (const float*)d_in[12];
  const float* diff_b2 = (const float*)d_in[13];
  const float* ep_w1 = (const float*)d_in[14];
  const float* ep_b1 = (const float*)d_in[15];
  const float* ep_w2 = (const float*)d_in[16];
  const float* ep_b2 = (const float*)d_in[17];
  const float* ref_w1 = (const float*)d_in[18];
  const float* ref_b1 = (const float*)d_in[19];
  const float* ref_g1 = (const float*)d_in[20];
  const float* ref_be1 = (const float*)d_in[21];

  float* out = (float*)d_out;
  float* out_prob = out + (size_t)NPT * C_;

  if (ws_size >= (size_t)(2 * 1024 * 1024)) {
    int* nidx_ws = (int*)d_ws;                             // 1 MB
    float* gf_ws = (float*)((char*)d_ws + (1u << 20));     // 768 KB
    knn_kernel<<<dim3(NPT / 8), dim3(256), 0, stream>>>(xyz, nidx_ws, gf_ws);
    mlp_kernel<<<dim3(NPT / 16), dim3(256), 0, stream>>>(
        features, nidx_ws, gf_ws, geo_w1, geo_b1, geo_g1, geo_be1, geo_w2,
        geo_b2, diff_w1, diff_b1, diff_g1, diff_be1, diff_w2, diff_b2, ep_w1,
        ep_b1, ep_w2, ep_b2, ref_w1, ref_b1, ref_g1, ref_be1, out, out_prob);
  } else {
    fused_kernel<<<dim3(NPT / 4), dim3(256), 0, stream>>>(
        xyz, features, geo_w1, geo_b1, geo_g1, geo_be1, geo_w2, geo_b2,
        diff_w1, diff_b1, diff_g1, diff_be1, diff_w2, diff_b2, ep_w1, ep_b1,
        ep_w2, ep_b2, ref_w1, ref_b1, ref_g1, ref_be1, out, out_prob);
  }
}

// Round 10
// 313.095 us; speedup vs baseline: 1.2641x; 1.2641x over previous
//
#include <hip/hip_runtime.h>
#include <hip/hip_bf16.h>

// B=4, N=4096, C=128, K=16. float32 in/out.
// R21 (eig QR arrays in LDS, 1pt/thread): 315.1us = SESSION BEST.
// R22 (eig fused into knn epilogue): REGRESSED 395.8 -- 2-lane gathers
//      tripled FETCH (33->116MB); and the QR chain wall (~60us) is FIXED
//      wherever it runs (R18 union-of-64 == R20 single-path). R21's
//      standalone 1pt/thread config is optimal: all 16384 pts in ONE wall.
// R23: exact R21 revert + knn tloc unroll 2->4 (R8-proven on same tile
//      structure; more ds_read_b128 in flight). Bit-identical.
// Component floors (measured): knn~128, eig~55, mlp~122, gaps~10.
#define N_ 4096
#define C_ 128
#define K_ 16
#define NPT 16384
#define ESTR 19  // 18 floats used + 1 pad; odd => 64 lanes spread all banks

__device__ __forceinline__ float wave_sum64(float v) {
#pragma unroll
  for (int off = 32; off >= 1; off >>= 1) v += __shfl_xor(v, off, 64);
  return v;
}

__device__ __forceinline__ float grp32_sum(float v) {
  v += __shfl_xor(v, 1, 64);
  v += __shfl_xor(v, 2, 64);
  v += __shfl_xor(v, 4, 64);
  v += __shfl_xor(v, 8, 64);
  v += __shfl_xor(v, 16, 64);
  return v;
}

// ---------------- LAPACK f32 helpers ----------------

__device__ __forceinline__ float sign_f(float a, float b) {
  return copysignf(fabsf(a), b);
}

__device__ float lapy2_f(float x, float y) {
#pragma clang fp contract(off)
  float xa = fabsf(x), ya = fabsf(y);
  float w = fmaxf(xa, ya), z = fminf(xa, ya);
  if (z == 0.0f) return w;
  float t = z / w;
  return w * sqrtf(1.0f + t * t);
}

__device__ void lartg_f(float f, float g, float& c, float& s, float& r) {
#pragma clang fp contract(off)
  if (g == 0.0f) {
    c = 1.0f; s = 0.0f; r = f;
  } else if (f == 0.0f) {
    c = 0.0f; s = copysignf(1.0f, g); r = fabsf(g);
  } else {
    float d = sqrtf(f * f + g * g);
    c = fabsf(f) / d;
    r = sign_f(d, f);
    s = g / r;
  }
}

__device__ void laev2_f(float a, float b, float cc, float& rt1, float& rt2,
                        float& cs1, float& sn1) {
#pragma clang fp contract(off)
  float sm = a + cc;
  float df = a - cc;
  float adf = fabsf(df);
  float tb = b + b;
  float ab = fabsf(tb);
  float acmx, acmn;
  if (fabsf(a) > fabsf(cc)) { acmx = a; acmn = cc; } else { acmx = cc; acmn = a; }
  float rt;
  if (adf > ab) {
    float t = ab / adf; rt = adf * sqrtf(1.0f + t * t);
  } else if (adf < ab) {
    float t = adf / ab; rt = ab * sqrtf(1.0f + t * t);
  } else {
    rt = ab * sqrtf(2.0f);
  }
  int sgn1;
  if (sm < 0.0f) {
    rt1 = 0.5f * (sm - rt); sgn1 = -1;
    rt2 = (acmx / rt1) * acmn - (b / rt1) * b;
  } else if (sm > 0.0f) {
    rt1 = 0.5f * (sm + rt); sgn1 = 1;
    rt2 = (acmx / rt1) * acmn - (b / rt1) * b;
  } else {
    rt1 = 0.5f * rt; rt2 = -0.5f * rt; sgn1 = 1;
  }
  float cs; int sgn2;
  if (df >= 0.0f) { cs = df + rt; sgn2 = 1; } else { cs = df - rt; sgn2 = -1; }
  float acs = fabsf(cs);
  if (acs > ab) {
    float ct = -tb / cs;
    sn1 = 1.0f / sqrtf(1.0f + ct * ct);
    cs1 = ct * sn1;
  } else {
    if (ab == 0.0f) { cs1 = 1.0f; sn1 = 0.0f; }
    else {
      float tn = -cs / tb;
      cs1 = 1.0f / sqrtf(1.0f + tn * tn);
      sn1 = tn * cs1;
    }
  }
  if (sgn1 == sgn2) { float tn = cs1; cs1 = -sn1; sn1 = tn; }
}

// LDS-backed variant: d[3] at d, e[2] at e, Z 3x3 row-major at Z (Z[r][c] ->
// Z[r*3+c]), csv[2], snv[2]. Arithmetic and control flow VERBATIM.
__device__ void steqr3_lds(float* __restrict__ d, float* __restrict__ e,
                           float* __restrict__ Z, float* __restrict__ csv,
                           float* __restrict__ snv) {
#pragma clang fp contract(off)
  const int n = 3;
  const float eps = 5.9604644775390625e-08f;
  const float eps2 = eps * eps;
  const float safmin = 1.17549435e-38f;
  const int nmaxit = n * 30;
  int jtot = 0;
  int l1 = 1;

  for (int og = 0; og < 16; ++og) {
    if (l1 > n) break;
    if (l1 > 1) e[l1 - 2] = 0.0f;
    int m, l, lend;
    if (l1 <= n - 1) {
      bool found = false;
      for (m = l1; m <= n - 1; ++m) {
        float tst = fabsf(e[m - 1]);
        if (tst == 0.0f) { found = true; break; }
        if (tst <= (sqrtf(fabsf(d[m - 1])) * sqrtf(fabsf(d[m]))) * eps) {
          e[m - 1] = 0.0f; found = true; break;
        }
      }
      if (!found) m = n;
    } else {
      m = n;
    }
    l = l1; lend = m; l1 = m + 1;
    if (lend == l) continue;
    if (fabsf(d[lend - 1]) < fabsf(d[l - 1])) { int t = l; l = lend; lend = t; }

    if (lend > l) {
      for (int it = 0; it < 128; ++it) {
        int mm;
        if (l != lend) {
          bool f2 = false;
          for (mm = l; mm <= lend - 1; ++mm) {
            float tst = e[mm - 1] * e[mm - 1];
            if (tst <= (eps2 * fabsf(d[mm - 1])) * fabsf(d[mm]) + safmin) { f2 = true; break; }
          }
          if (!f2) mm = lend;
        } else mm = lend;
        if (mm < lend) e[mm - 1] = 0.0f;
        float p = d[l - 1];
        if (mm == l) {
          d[l - 1] = p; ++l;
          if (l <= lend) continue;
          break;
        }
        if (mm == l + 1) {
          float rt1, rt2, cc, ss;
          laev2_f(d[l - 1], e[l - 1], d[l], rt1, rt2, cc, ss);
          for (int r = 0; r < n; ++r) {
            float temp = Z[r * 3 + l];
            Z[r * 3 + l] = cc * temp - ss * Z[r * 3 + l - 1];
            Z[r * 3 + l - 1] = ss * temp + cc * Z[r * 3 + l - 1];
          }
          d[l - 1] = rt1; d[l] = rt2; e[l - 1] = 0.0f;
          l += 2;
          if (l <= lend) continue;
          break;
        }
        if (jtot == nmaxit) break;
        ++jtot;
        float g = (d[l] - p) / (2.0f * e[l - 1]);
        float r = lapy2_f(g, 1.0f);
        g = d[mm - 1] - p + e[l - 1] / (g + sign_f(r, g));
        float s = 1.0f, c = 1.0f;
        p = 0.0f;
        for (int i = mm - 1; i >= l; --i) {
          float f = s * e[i - 1];
          float bb = c * e[i - 1];
          lartg_f(g, f, c, s, r);
          if (i != mm - 1) e[i] = r;
          g = d[i] - p;
          r = (d[i - 1] - g) * s + 2.0f * c * bb;
          p = s * r;
          d[i] = g + p;
          g = c * r - bb;
          csv[i - l] = c;
          snv[i - l] = -s;
        }
        int mml = mm - l;
        for (int j = mml; j >= 1; --j) {
          float cc = csv[j - 1], ss = snv[j - 1];
          for (int r2 = 0; r2 < n; ++r2) {
            float temp = Z[r2 * 3 + l + j - 1];
            Z[r2 * 3 + l + j - 1] = cc * temp - ss * Z[r2 * 3 + l + j - 2];
            Z[r2 * 3 + l + j - 2] = ss * temp + cc * Z[r2 * 3 + l + j - 2];
          }
        }
        d[l - 1] -= p;
        e[l - 1] = g;
      }
    } else {
      for (int it = 0; it < 128; ++it) {
        int mm;
        if (l != lend) {
          bool f2 = false;
          for (mm = l; mm >= lend + 1; --mm) {
            float tst = e[mm - 2] * e[mm - 2];
            if (tst <= (eps2 * fabsf(d[mm - 1])) * fabsf(d[mm - 2]) + safmin) { f2 = true; break; }
          }
          if (!f2) mm = lend;
        } else mm = lend;
        if (mm > lend) e[mm - 2] = 0.0f;
        float p = d[l - 1];
        if (mm == l) {
          d[l - 1] = p; --l;
          if (l >= lend) continue;
          break;
        }
        if (mm == l - 1) {
          float rt1, rt2, cc, ss;
          laev2_f(d[l - 2], e[l - 2], d[l - 1], rt1, rt2, cc, ss);
          for (int r = 0; r < n; ++r) {
            float temp = Z[r * 3 + l - 1];
            Z[r * 3 + l - 1] = cc * temp - ss * Z[r * 3 + l - 2];
            Z[r * 3 + l - 2] = ss * temp + cc * Z[r * 3 + l - 2];
          }
          d[l - 2] = rt1; d[l - 1] = rt2; e[l - 2] = 0.0f;
          l -= 2;
          if (l >= lend) continue;
          break;
        }
        if (jtot == nmaxit) break;
        ++jtot;
        float g = (d[l - 2] - p) / (2.0f * e[l - 2]);
        float r = lapy2_f(g, 1.0f);
        g = d[mm - 1] - p + e[l - 2] / (g + sign_f(r, g));
        float s = 1.0f, c = 1.0f;
        p = 0.0f;
        for (int i = mm; i <= l - 1; ++i) {
          float f = s * e[i - 1];
          float bb = c * e[i - 1];
          lartg_f(g, f, c, s, r);
          if (i != mm) e[i - 2] = r;
          g = d[i - 1] - p;
          r = (d[i] - g) * s + 2.0f * c * bb;
          p = s * r;
          d[i - 1] = g + p;
          g = c * r - bb;
          csv[i - mm] = c;
          snv[i - mm] = s;
        }
        int lm = l - mm;
        for (int j = 1; j <= lm; ++j) {
          float cc = csv[j - 1], ss = snv[j - 1];
          for (int r2 = 0; r2 < n; ++r2) {
            float temp = Z[r2 * 3 + mm + j - 1];
            Z[r2 * 3 + mm + j - 1] = cc * temp - ss * Z[r2 * 3 + mm + j - 2];
            Z[r2 * 3 + mm + j - 2] = ss * temp + cc * Z[r2 * 3 + mm + j - 2];
          }
        }
        d[l - 1] -= p;
        e[l - 2] = g;
      }
    }
  }
  for (int ii = 2; ii <= n; ++ii) {
    int i = ii - 1, k = i;
    float p = d[i - 1];
    for (int j = ii; j <= n; ++j) {
      if (d[j - 1] < p) { k = j; p = d[j - 1]; }
    }
    if (k != i) {
      d[k - 1] = d[i - 1]; d[i - 1] = p;
      for (int r = 0; r < n; ++r) {
        float t = Z[r * 3 + i - 1]; Z[r * 3 + i - 1] = Z[r * 3 + k - 1]; Z[r * 3 + k - 1] = t;
      }
    }
  }
}

// LDS-backed eig3: base slice layout: d=base+0(3), e=base+3(2), Z=base+5(9),
// csv=base+14(2), snv=base+16(2). Arithmetic VERBATIM from eig3_f.
__device__ void eig3_lds(float A00, float A10, float A20,
                         float A11, float A21, float A22, float* __restrict__ base) {
#pragma clang fp contract(off)
  float* d = base;
  float* e = base + 3;
  float* Z = base + 5;
  float* csv = base + 14;
  float* snv = base + 16;
  float tau = 0.0f, v2 = 0.0f;
  d[0] = A00;
  float xnorm = fabsf(A20);
  if (xnorm == 0.0f) {
    tau = 0.0f; v2 = 0.0f;
    e[0] = A10; d[1] = A11; e[1] = A21; d[2] = A22;
  } else {
    float beta = -sign_f(lapy2_f(A10, xnorm), A10);
    tau = (beta - A10) / beta;
    float inv = 1.0f / (A10 - beta);
    v2 = A20 * inv;
    e[0] = beta;
    float x0 = tau * A11;
    float x1 = tau * A21;
    float tmp2 = A21 * v2;
    x0 = x0 + tau * tmp2;
    x1 = x1 + (tau * v2) * A22;
    float dotv = x0 + x1 * v2;
    float aw = (-0.5f * tau) * dotv;
    float w0 = x0 + aw;
    float w1 = x1 + aw * v2;
    d[1] = (A11 - w0) - w0;
    float pq = v2 * w0;
    e[1] = (A21 - pq) - w1;
    float pr = v2 * w1;
    d[2] = (A22 - pr) - pr;
  }
  Z[0] = 1.0f; Z[1] = 0.0f; Z[2] = 0.0f;
  Z[3] = 0.0f; Z[4] = 1.0f; Z[5] = 0.0f;
  Z[6] = 0.0f; Z[7] = 0.0f; Z[8] = 1.0f;
  steqr3_lds(d, e, Z, csv, snv);
  if (tau != 0.0f) {
    for (int j = 0; j < 3; ++j) {
      float sum = Z[3 + j] + v2 * Z[6 + j];
      float tw = tau * sum;
      Z[3 + j] = Z[3 + j] - tw;
      Z[6 + j] = Z[6 + j] - v2 * tw;
    }
  }
}

// Register-array variant kept for the fallback fused_kernel (proven path).
__device__ void steqr3_f(float d[3], float e[2], float Z[3][3]) {
#pragma clang fp contract(off)
  float csv[2], snv[2];
  steqr3_lds(d, e, &Z[0][0], csv, snv);
}

__device__ void eig3_f(float A00, float A10, float A20,
                       float A11, float A21, float A22, float Z[3][3]) {
#pragma clang fp contract(off)
  float d[3], e[2];
  float tau = 0.0f, v2 = 0.0f;
  d[0] = A00;
  float xnorm = fabsf(A20);
  if (xnorm == 0.0f) {
    tau = 0.0f; v2 = 0.0f;
    e[0] = A10; d[1] = A11; e[1] = A21; d[2] = A22;
  } else {
    float beta = -sign_f(lapy2_f(A10, xnorm), A10);
    tau = (beta - A10) / beta;
    float inv = 1.0f / (A10 - beta);
    v2 = A20 * inv;
    e[0] = beta;
    float x0 = tau * A11;
    float x1 = tau * A21;
    float tmp2 = A21 * v2;
    x0 = x0 + tau * tmp2;
    x1 = x1 + (tau * v2) * A22;
    float dotv = x0 + x1 * v2;
    float aw = (-0.5f * tau) * dotv;
    float w0 = x0 + aw;
    float w1 = x1 + aw * v2;
    d[1] = (A11 - w0) - w0;
    float pq = v2 * w0;
    e[1] = (A21 - pq) - w1;
    float pr = v2 * w1;
    d[2] = (A22 - pr) - pr;
  }
  Z[0][0] = 1.0f; Z[0][1] = 0.0f; Z[0][2] = 0.0f;
  Z[1][0] = 0.0f; Z[1][1] = 1.0f; Z[1][2] = 0.0f;
  Z[2][0] = 0.0f; Z[2][1] = 0.0f; Z[2][2] = 1.0f;
  steqr3_f(d, e, Z);
  if (tau != 0.0f) {
    for (int j = 0; j < 3; ++j) {
      float sum = Z[1][j] + v2 * Z[2][j];
      float tw = tau * sum;
      Z[1][j] = Z[1][j] - tw;
      Z[2][j] = Z[2][j] - v2 * tw;
    }
  }
}

// ---------------- KNN key (numpy-f32-faithful) ----------------
__device__ __forceinline__ unsigned long long knn_key(float qx, float qy, float qz,
                                                      float nqxx, float x, float y,
                                                      float z, int j) {
  const float dot = __fmaf_rn(qz, z, __fmaf_rn(qy, y, __fmul_rn(qx, x)));
  const float xxj =
      __fadd_rn(__fadd_rn(__fmul_rn(x, x), __fmul_rn(y, y)), __fmul_rn(z, z));
  const float inner = __fmul_rn(-2.0f, dot);
  const float pval = __fsub_rn(__fsub_rn(nqxx, inner), xxj);
  const unsigned bits = __float_as_uint(pval);
  const unsigned ordv = bits ^ (unsigned)(((int)bits >> 31) | 0x80000000);
  return ((unsigned long long)ordv << 32) | (unsigned)(4095 - j);
}

// ---------------- Kernel A1: KNN, 2 query points per wave, 8 pts/block ----------------
__global__ __launch_bounds__(256, 6) void knn_kernel(const float* __restrict__ xyz,
                                                     int* __restrict__ nidx_ws) {
  __shared__ float4 tile4[1024];   // (x,y,z,xx) per candidate: 1 ds_read_b128/cand

  const int wave = threadIdx.x >> 6;
  const int lane = threadIdx.x & 63;
  const int tid = threadIdx.x;
  const int P0 = blockIdx.x * 8;        // 8 points/block (2 per wave)
  const int b = P0 >> 12;
  const int r0 = P0 & 4095;
  const int pbase = r0 + wave * 2;
  const float* xb = xyz + (size_t)b * (N_ * 3);

  float qx[2], qy[2], qz[2], nqxx[2];
#pragma unroll
  for (int q = 0; q < 2; ++q) {
    const int i = pbase + q;
    qx[q] = xb[3 * i]; qy[q] = xb[3 * i + 1]; qz[q] = xb[3 * i + 2];
    nqxx[q] = -__fadd_rn(__fadd_rn(__fmul_rn(qx[q], qx[q]), __fmul_rn(qy[q], qy[q])),
                         __fmul_rn(qz[q], qz[q]));
  }

  unsigned long long pk[2][4];
#pragma unroll
  for (int q = 0; q < 2; ++q)
#pragma unroll
    for (int s = 0; s < 4; ++s) pk[q][s] = 0ull;

  for (int tile = 0; tile < 4; ++tile) {
    {
      const float4* gsrc = (const float4*)(xb + tile * 3072);
      float4 a0 = gsrc[tid * 3];
      float4 a1 = gsrc[tid * 3 + 1];
      float4 a2 = gsrc[tid * 3 + 2];
      const int base = tid * 4;
      const float xx0 = __fadd_rn(__fadd_rn(__fmul_rn(a0.x, a0.x), __fmul_rn(a0.y, a0.y)), __fmul_rn(a0.z, a0.z));
      const float xx1 = __fadd_rn(__fadd_rn(__fmul_rn(a0.w, a0.w), __fmul_rn(a1.x, a1.x)), __fmul_rn(a1.y, a1.y));
      const float xx2 = __fadd_rn(__fadd_rn(__fmul_rn(a1.z, a1.z), __fmul_rn(a1.w, a1.w)), __fmul_rn(a2.x, a2.x));
      const float xx3 = __fadd_rn(__fadd_rn(__fmul_rn(a2.y, a2.y), __fmul_rn(a2.z, a2.z)), __fmul_rn(a2.w, a2.w));
      tile4[base]     = make_float4(a0.x, a0.y, a0.z, xx0);
      tile4[base + 1] = make_float4(a0.w, a1.x, a1.y, xx1);
      tile4[base + 2] = make_float4(a1.z, a1.w, a2.x, xx2);
      tile4[base + 3] = make_float4(a2.y, a2.z, a2.w, xx3);
    }
    __syncthreads();

#pragma unroll 4
    for (int tloc = 0; tloc < 16; ++tloc) {
      const int idx = tloc * 64 + lane;
      const int j = tile * 1024 + idx;
      const float4 pv = tile4[idx];
      const float x = pv.x;
      const float y = pv.y;
      const float z = pv.z;
      const float xxj = pv.w;
      const unsigned jenc = (unsigned)(4095 - j);
#pragma unroll
      for (int q = 0; q < 2; ++q) {
        const float dot =
            __fmaf_rn(qz[q], z, __fmaf_rn(qy[q], y, __fmul_rn(qx[q], x)));
        const float inner = __fmul_rn(-2.0f, dot);
        const float pval = __fsub_rn(__fsub_rn(nqxx[q], inner), xxj);
        const unsigned bits = __float_as_uint(pval);
        const unsigned ordv = bits ^ (unsigned)(((int)bits >> 31) | 0x80000000);
        const unsigned long long key = ((unsigned long long)ordv << 32) | jenc;
        const bool c3 = key > pk[q][3];
        if (__any(c3)) {
          const bool c0 = key > pk[q][0], c1 = key > pk[q][1], c2 = key > pk[q][2];
          pk[q][3] = c3 ? (c2 ? pk[q][2] : key) : pk[q][3];
          pk[q][2] = c2 ? (c1 ? pk[q][1] : key) : pk[q][2];
          pk[q][1] = c1 ? (c0 ? pk[q][0] : key) : pk[q][1];
          pk[q][0] = c0 ? key : pk[q][0];
        }
      }
    }
    __syncthreads();
  }

  int stash[2];
  int h[2] = {0, 0};
#pragma unroll
  for (int k = 0; k < K_; ++k) {
    unsigned long long v[2];
#pragma unroll
    for (int q = 0; q < 2; ++q) v[q] = pk[q][0];
#pragma unroll
    for (int off = 32; off >= 1; off >>= 1) {
#pragma unroll
      for (int q = 0; q < 2; ++q) {
        unsigned long long ov = __shfl_xor(v[q], off, 64);
        if (ov > v[q]) v[q] = ov;
      }
    }
#pragma unroll
    for (int q = 0; q < 2; ++q) {
      const int jidx = (4095 - (int)(unsigned)(v[q] & 0xFFFFFFFFull)) & (N_ - 1);
      if (lane == k) stash[q] = jidx;
      if (pk[q][0] == v[q]) {
        pk[q][0] = pk[q][1]; pk[q][1] = pk[q][2]; pk[q][2] = pk[q][3];
        pk[q][3] = 0ull;
        ++h[q];
      }
    }
  }
#pragma unroll
  for (int q = 0; q < 2; ++q) {
    if (__ballot(h[q] >= 4) != 0ull) {
      unsigned long long qq[K_];
#pragma unroll
      for (int k = 0; k < K_; ++k) qq[k] = 0ull;
      for (int t = 0; t < 64; ++t) {
        const int j = t * 64 + lane;
        const unsigned long long key = knn_key(qx[q], qy[q], qz[q], nqxx[q],
                                               xb[3 * j], xb[3 * j + 1],
                                               xb[3 * j + 2], j);
        bool c[K_];
#pragma unroll
        for (int s = 0; s < K_; ++s) c[s] = key > qq[s];
#pragma unroll
        for (int s = K_ - 1; s >= 1; --s)
          qq[s] = c[s] ? (c[s - 1] ? qq[s - 1] : key) : qq[s];
        qq[0] = c[0] ? key : qq[0];
      }
#pragma unroll
      for (int k = 0; k < K_; ++k) {
        unsigned long long v = qq[0];
#pragma unroll
        for (int off = 32; off >= 1; off >>= 1) {
          unsigned long long ov = __shfl_xor(v, off, 64);
          if (ov > v) v = ov;
        }
        const int jidx = (4095 - (int)(unsigned)(v & 0xFFFFFFFFull)) & (N_ - 1);
        if (lane == k) stash[q] = jidx;
        if (qq[0] == v) {
#pragma unroll
          for (int s = 0; s < K_ - 1; ++s) qq[s] = qq[s + 1];
          qq[K_ - 1] = 0ull;
        }
      }
    }
  }

  if (lane < K_) {
    const int pg = P0 + wave * 2;
#pragma unroll
    for (int q = 0; q < 2; ++q)
      nidx_ws[(size_t)(pg + q) * K_ + lane] = stash[q];
  }
}

// ---------------- Kernel A2: cov + eig, 1pt/thread, QR arrays in LDS (R21) ----------------
__global__ __launch_bounds__(64) void eig_kernel(const float* __restrict__ xyz,
                                                 const int* __restrict__ nidx_ws,
                                                 float* __restrict__ gf_ws) {
  __shared__ float ework[64 * ESTR];
  float* base = ework + threadIdx.x * ESTR;

  const int p = blockIdx.x * 64 + threadIdx.x;
  const int b = p >> 12;
  const int i = p & 4095;
  const float* xb = xyz + (size_t)b * (N_ * 3);
  const float qx = xb[3 * i];
  const float qy = xb[3 * i + 1];
  const float qz = xb[3 * i + 2];

  int nidx[K_];
#pragma unroll
  for (int k = 0; k < K_; ++k) nidx[k] = nidx_ws[(size_t)p * K_ + k];

  float c00 = 0, c01 = 0, c02 = 0, c11 = 0, c12 = 0, c22 = 0;
  float mrx = 0, mry = 0, mrz = 0, md = 0;
#pragma unroll
  for (int k = 0; k < K_; ++k) {
    const int j = nidx[k];
    const float rx = __fsub_rn(xb[3 * j], qx);
    const float ry = __fsub_rn(xb[3 * j + 1], qy);
    const float rz = __fsub_rn(xb[3 * j + 2], qz);
    c00 = __fadd_rn(c00, __fmul_rn(rx, rx));
    c01 = __fadd_rn(c01, __fmul_rn(rx, ry));
    c02 = __fadd_rn(c02, __fmul_rn(rx, rz));
    c11 = __fadd_rn(c11, __fmul_rn(ry, ry));
    c12 = __fadd_rn(c12, __fmul_rn(ry, rz));
    c22 = __fadd_rn(c22, __fmul_rn(rz, rz));
    mrx = __fadd_rn(mrx, rx);
    mry = __fadd_rn(mry, ry);
    mrz = __fadd_rn(mrz, rz);
    const float nn = __fadd_rn(__fadd_rn(__fmul_rn(rx, rx), __fmul_rn(ry, ry)),
                               __fmul_rn(rz, rz));
    md = __fadd_rn(md, sqrtf(nn));
  }
  const float s16 = 0.0625f;
  eig3_lds(__fmul_rn(c00, s16), __fmul_rn(c01, s16), __fmul_rn(c02, s16),
           __fmul_rn(c11, s16), __fmul_rn(c12, s16), __fmul_rn(c22, s16), base);
  const float* Z = base + 5;   // row-major 3x3
  float* g = gf_ws + (size_t)p * 12;
  g[0] = Z[0]; g[1] = Z[3]; g[2] = Z[6];    // eigvec col 0 (normal)
  g[3] = Z[2]; g[4] = Z[5]; g[5] = Z[8];    // eigvec col 2 (curvature)
  g[6] = __fmul_rn(mrx, s16); g[7] = __fmul_rn(mry, s16);
  g[8] = __fmul_rn(mrz, s16);
  g[9] = __fmul_rn(md, s16);
}

// ---------------- Kernel B: block-cooperative MLPs (R16 + R18, proven) ----------------
__global__ __launch_bounds__(256) void mlp_kernel(
    const float* __restrict__ feats, const int* __restrict__ nidx_ws,
    const float* __restrict__ gf_ws,
    const float* __restrict__ geo_w1, const float* __restrict__ geo_b1,
    const float* __restrict__ geo_g1, const float* __restrict__ geo_be1,
    const float* __restrict__ geo_w2, const float* __restrict__ geo_b2,
    const float* __restrict__ diff_w1, const float* __restrict__ diff_b1,
    const float* __restrict__ diff_g1, const float* __restrict__ diff_be1,
    const float* __restrict__ diff_w2, const float* __restrict__ diff_b2,
    const float* __restrict__ ep_w1, const float* __restrict__ ep_b1,
    const float* __restrict__ ep_w2, const float* __restrict__ ep_b2,
    const float* __restrict__ ref_w1, const float* __restrict__ ref_b1,
    const float* __restrict__ ref_g1, const float* __restrict__ ref_be1,
    float* __restrict__ out, float* __restrict__ out_prob) {

  __shared__ float w[8192];
  __shared__ float fsh[16 * 128];
  __shared__ float sdif[16 * 128];
  __shared__ float ysh[16 * 64];
  __shared__ float edsh[16 * 128];
  __shared__ float insh[16 * 12];
  __shared__ int nsh[16 * 16];

  const int tid = threadIdx.x;
  const int lane = tid & 63;
  const int g = tid >> 6;
  const int P0 = blockIdx.x * 16;
  const int b = P0 >> 12;
  const int r0 = P0 & 4095;
  const float* fb = feats + (size_t)b * N_ * C_;

  if (tid < 192) insh[tid] = gf_ws[(size_t)P0 * 12 + tid];
  nsh[tid] = nidx_ws[(size_t)P0 * K_ + tid];
#pragma unroll
  for (int m = 0; m < 8; ++m)
    fsh[m * 256 + tid] = fb[(size_t)r0 * C_ + m * 256 + tid];
  if (tid < 160) ((float4*)w)[tid] = ((const float4*)geo_w1)[tid];
#pragma unroll
  for (int m = 0; m < 4; ++m)
    ((float4*)(w + 640))[m * 256 + tid] = ((const float4*)geo_w2)[m * 256 + tid];
  __syncthreads();

  // geo layer 1 (channel-outer, R12 unchanged) + LN
  {
    float acc[4] = {0, 0, 0, 0};
#pragma unroll
    for (int c = 0; c < 10; ++c) {
      const float wv = w[c * 64 + lane];
#pragma unroll
      for (int ptl = 0; ptl < 4; ++ptl)
        acc[ptl] += insh[(g * 4 + ptl) * 12 + c] * wv;
    }
#pragma unroll
    for (int ptl = 0; ptl < 4; ++ptl) {
      const int pt = g * 4 + ptl;
      float a = acc[ptl] + geo_b1[lane];
      float m = wave_sum64(a) * (1.0f / 64.0f);
      float xm = a - m;
      float var = wave_sum64(xm * xm) * (1.0f / 64.0f);
      float yv = xm * (1.0f / sqrtf(var + 1e-5f)) * geo_g1[lane] + geo_be1[lane];
      ysh[pt * 64 + lane] = fmaxf(yv, 0.0f);
    }
  }
  __syncthreads();

  // geo layer 2: R12 weights + float4 activation broadcasts (R18)
  float ge[4] = {0, 0, 0, 0}, de[4], prob[4];
#pragma unroll 2
  for (int c4 = 0; c4 < 64; c4 += 4) {
    const float w0 = w[640 + (c4 + 0) * 64 + lane];
    const float w1 = w[640 + (c4 + 1) * 64 + lane];
    const float w2 = w[640 + (c4 + 2) * 64 + lane];
    const float w3 = w[640 + (c4 + 3) * 64 + lane];
#pragma unroll
    for (int ptl = 0; ptl < 4; ++ptl) {
      const float4 yv = *(const float4*)(ysh + (g * 4 + ptl) * 64 + c4);
      ge[ptl] += yv.x * w0; ge[ptl] += yv.y * w1;
      ge[ptl] += yv.z * w2; ge[ptl] += yv.w * w3;
    }
  }
#pragma unroll
  for (int ptl = 0; ptl < 4; ++ptl) ge[ptl] += geo_b2[lane];

  // feat_diff: float4 gathers (R17-proven); 8 groups of 32 threads, 2 points each.
  {
    const int grp = tid >> 5;
    const int c4 = (tid & 31) * 4;
#pragma unroll
    for (int pp = 0; pp < 2; ++pp) {
      const int pt = grp * 2 + pp;
      const float4 fv = *(const float4*)(fsh + pt * 128 + c4);
      float s0 = 0, s1 = 0, s2 = 0, s3 = 0;
      for (int k = 0; k < K_; ++k) {
        const int j = nsh[pt * 16 + k];
        const float4 a = *(const float4*)(fb + (size_t)j * C_ + c4);
        s0 += fabsf(fv.x - a.x);
        s1 += fabsf(fv.y - a.y);
        s2 += fabsf(fv.z - a.z);
        s3 += fabsf(fv.w - a.w);
      }
      const float sc = 1.0f / 16.0f;
      *(float4*)(sdif + pt * 128 + c4) =
          make_float4(s0 * sc, s1 * sc, s2 * sc, s3 * sc);
    }
  }
  __syncthreads();
#pragma unroll
  for (int m = 0; m < 8; ++m)
    ((float4*)w)[m * 256 + tid] = ((const float4*)diff_w1)[m * 256 + tid];
  __syncthreads();

  // diff layer 1: R12 weights + float4 activation broadcasts + LN (R12 LN)
  {
    float acc[4] = {0, 0, 0, 0};
#pragma unroll 2
    for (int c4 = 0; c4 < 128; c4 += 4) {
      const float w0 = w[(c4 + 0) * 64 + lane];
      const float w1 = w[(c4 + 1) * 64 + lane];
      const float w2 = w[(c4 + 2) * 64 + lane];
      const float w3 = w[(c4 + 3) * 64 + lane];
#pragma unroll
      for (int ptl = 0; ptl < 4; ++ptl) {
        const float4 sv = *(const float4*)(sdif + (g * 4 + ptl) * 128 + c4);
        acc[ptl] += sv.x * w0; acc[ptl] += sv.y * w1;
        acc[ptl] += sv.z * w2; acc[ptl] += sv.w * w3;
      }
    }
#pragma unroll
    for (int ptl = 0; ptl < 4; ++ptl) {
      const int pt = g * 4 + ptl;
      float a = acc[ptl] + diff_b1[lane];
      float m = wave_sum64(a) * (1.0f / 64.0f);
      float xm = a - m;
      float var = wave_sum64(xm * xm) * (1.0f / 64.0f);
      float yv = xm * (1.0f / sqrtf(var + 1e-5f)) * diff_g1[lane] + diff_be1[lane];
      ysh[pt * 64 + lane] = fmaxf(yv, 0.0f);
    }
  }
  __syncthreads();
#pragma unroll
  for (int m = 0; m < 4; ++m)
    ((float4*)w)[m * 256 + tid] = ((const float4*)diff_w2)[m * 256 + tid];
#pragma unroll
  for (int m = 0; m < 4; ++m)
    ((float4*)w)[1024 + m * 256 + tid] = ((const float4*)ep_w1)[m * 256 + tid];
  __syncthreads();

  // diff layer 2: R12 weights + float4 activations, stash [ge||de]
  {
    float acc[4] = {0, 0, 0, 0};
#pragma unroll 2
    for (int c4 = 0; c4 < 64; c4 += 4) {
      const float w0 = w[(c4 + 0) * 64 + lane];
      const float w1 = w[(c4 + 1) * 64 + lane];
      const float w2 = w[(c4 + 2) * 64 + lane];
      const float w3 = w[(c4 + 3) * 64 + lane];
#pragma unroll
      for (int ptl = 0; ptl < 4; ++ptl) {
        const float4 yv = *(const float4*)(ysh + (g * 4 + ptl) * 64 + c4);
        acc[ptl] += yv.x * w0; acc[ptl] += yv.y * w1;
        acc[ptl] += yv.z * w2; acc[ptl] += yv.w * w3;
      }
    }
#pragma unroll
    for (int ptl = 0; ptl < 4; ++ptl) {
      const int pt = g * 4 + ptl;
      de[ptl] = acc[ptl] + diff_b2[lane];
      edsh[pt * 128 + lane] = ge[ptl];
      edsh[pt * 128 + 64 + lane] = de[ptl];
    }
  }
  __syncthreads();

  // edge-prob MLP: R12 weights + float4 activations; reduction/sigmoid R12
  const int u = lane & 31;
  {
    float ea[4] = {0, 0, 0, 0};
#pragma unroll 2
    for (int c4 = 0; c4 < 128; c4 += 4) {
      const float w0 = w[4096 + (c4 + 0) * 32 + u];
      const float w1 = w[4096 + (c4 + 1) * 32 + u];
      const float w2 = w[4096 + (c4 + 2) * 32 + u];
      const float w3 = w[4096 + (c4 + 3) * 32 + u];
#pragma unroll
      for (int ptl = 0; ptl < 4; ++ptl) {
        const float4 ev = *(const float4*)(edsh + (g * 4 + ptl) * 128 + c4);
        ea[ptl] += ev.x * w0; ea[ptl] += ev.y * w1;
        ea[ptl] += ev.z * w2; ea[ptl] += ev.w * w3;
      }
    }
#pragma unroll
    for (int ptl = 0; ptl < 4; ++ptl) {
      float a = ea[ptl] + ep_b1[u];
      float hh = (lane < 32) ? fmaxf(a, 0.0f) * ep_w2[u] : 0.0f;
      float tsum = wave_sum64(hh) + ep_b2[0];
      prob[ptl] = 1.0f / (1.0f + expf(-tsum));
      if (lane == 0) out_prob[P0 + g * 4 + ptl] = prob[ptl];
    }
  }
  __syncthreads();
#pragma unroll
  for (int ptl = 0; ptl < 4; ++ptl) {
    const int pt = g * 4 + ptl;
    edsh[pt * 128 + lane] = ge[ptl] * prob[ptl];
    edsh[pt * 128 + 64 + lane] = de[ptl] * prob[ptl];
  }

  // ---- ref matvec (R16 map C, proven): thread -> (ptA,ptB, 4 consecutive out-ch) ----
  const int p2 = tid >> 5;
  const int ptA = p2 * 2, ptB = ptA + 1;
  const int oc4 = (tid & 31) * 4;
  float A0 = 0, A1 = 0, A2 = 0, A3 = 0;
  float B0 = 0, B1 = 0, B2 = 0, B3 = 0;
  for (int ch = 0; ch < 4; ++ch) {
    __syncthreads();
    {
      const float4* gsrc = (const float4*)(ref_w1 + ch * 8192);
#pragma unroll
      for (int m = 0; m < 8; ++m) ((float4*)w)[m * 256 + tid] = gsrc[m * 256 + tid];
    }
    __syncthreads();
    const float* eA = (ch < 2) ? (fsh + ptA * 128 + ch * 64)
                               : (edsh + ptA * 128 + (ch - 2) * 64);
    const float* eB = (ch < 2) ? (fsh + ptB * 128 + ch * 64)
                               : (edsh + ptB * 128 + (ch - 2) * 64);
#pragma unroll 4
    for (int c4 = 0; c4 < 64; c4 += 4) {
      const float4 ea = *(const float4*)(eA + c4);
      const float4 eb = *(const float4*)(eB + c4);
      const float4 w0 = *(const float4*)(w + (c4 + 0) * 128 + oc4);
      const float4 w1 = *(const float4*)(w + (c4 + 1) * 128 + oc4);
      const float4 w2 = *(const float4*)(w + (c4 + 2) * 128 + oc4);
      const float4 w3 = *(const float4*)(w + (c4 + 3) * 128 + oc4);
      A0 += ea.x * w0.x; A0 += ea.y * w1.x; A0 += ea.z * w2.x; A0 += ea.w * w3.x;
      A1 += ea.x * w0.y; A1 += ea.y * w1.y; A1 += ea.z * w2.y; A1 += ea.w * w3.y;
      A2 += ea.x * w0.z; A2 += ea.y * w1.z; A2 += ea.z * w2.z; A2 += ea.w * w3.z;
      A3 += ea.x * w0.w; A3 += ea.y * w1.w; A3 += ea.z * w2.w; A3 += ea.w * w3.w;
      B0 += eb.x * w0.x; B0 += eb.y * w1.x; B0 += eb.z * w2.x; B0 += eb.w * w3.x;
      B1 += eb.x * w0.y; B1 += eb.y * w1.y; B1 += eb.z * w2.y; B1 += eb.w * w3.y;
      B2 += eb.x * w0.z; B2 += eb.y * w1.z; B2 += eb.z * w2.z; B2 += eb.w * w3.z;
      B3 += eb.x * w0.w; B3 += eb.y * w1.w; B3 += eb.z * w2.w; B3 += eb.w * w3.w;
    }
  }

  // ---- epilogue (map C): LN over 128 ch = 32 lanes x 4, relu, residual ----
  {
    const float4 rb = *(const float4*)(ref_b1 + oc4);
    A0 += rb.x; A1 += rb.y; A2 += rb.z; A3 += rb.w;
    B0 += rb.x; B1 += rb.y; B2 += rb.z; B3 += rb.w;
    const float4 gg = *(const float4*)(ref_g1 + oc4);
    const float4 be = *(const float4*)(ref_be1 + oc4);

    const float mA = grp32_sum(A0 + A1 + A2 + A3) * (1.0f / 128.0f);
    const float dA0 = A0 - mA, dA1 = A1 - mA, dA2 = A2 - mA, dA3 = A3 - mA;
    const float vA =
        grp32_sum(dA0 * dA0 + dA1 * dA1 + dA2 * dA2 + dA3 * dA3) * (1.0f / 128.0f);
    const float rsA = 1.0f / sqrtf(vA + 1e-5f);
    const float4 resA = *(const float4*)(fsh + ptA * 128 + oc4);
    float4 yA;
    yA.x = fmaxf(dA0 * rsA * gg.x + be.x, 0.0f) + resA.x;
    yA.y = fmaxf(dA1 * rsA * gg.y + be.y, 0.0f) + resA.y;
    yA.z = fmaxf(dA2 * rsA * gg.z + be.z, 0.0f) + resA.z;
    yA.w = fmaxf(dA3 * rsA * gg.w + be.w, 0.0f) + resA.w;
    *(float4*)(out + (size_t)(P0 + ptA) * 128 + oc4) = yA;

    const float mB = grp32_sum(B0 + B1 + B2 + B3) * (1.0f / 128.0f);
    const float dB0 = B0 - mB, dB1 = B1 - mB, dB2 = B2 - mB, dB3 = B3 - mB;
    const float vB =
        grp32_sum(dB0 * dB0 + dB1 * dB1 + dB2 * dB2 + dB3 * dB3) * (1.0f / 128.0f);
    const float rsB = 1.0f / sqrtf(vB + 1e-5f);
    const float4 resB = *(const float4*)(fsh + ptB * 128 + oc4);
    float4 yB;
    yB.x = fmaxf(dB0 * rsB * gg.x + be.x, 0.0f) + resB.x;
    yB.y = fmaxf(dB1 * rsB * gg.y + be.y, 0.0f) + resB.y;
    yB.z = fmaxf(dB2 * rsB * gg.z + be.z, 0.0f) + resB.z;
    yB.w = fmaxf(dB3 * rsB * gg.w + be.w, 0.0f) + resB.w;
    *(float4*)(out + (size_t)(P0 + ptB) * 128 + oc4) = yB;
  }
}

// ---------------- Fallback: R8 fused kernel (proven) ----------------
__global__ __launch_bounds__(256) void fused_kernel(
    const float* __restrict__ xyz, const float* __restrict__ feats,
    const float* __restrict__ geo_w1, const float* __restrict__ geo_b1,
    const float* __restrict__ geo_g1, const float* __restrict__ geo_be1,
    const float* __restrict__ geo_w2, const float* __restrict__ geo_b2,
    const float* __restrict__ diff_w1, const float* __restrict__ diff_b1,
    const float* __restrict__ diff_g1, const float* __restrict__ diff_be1,
    const float* __restrict__ diff_w2, const float* __restrict__ diff_b2,
    const float* __restrict__ ep_w1, const float* __restrict__ ep_b1,
    const float* __restrict__ ep_w2, const float* __restrict__ ep_b2,
    const float* __restrict__ ref_w1, const float* __restrict__ ref_b1,
    const float* __restrict__ ref_g1, const float* __restrict__ ref_be1,
    float* __restrict__ out, float* __restrict__ out_prob) {

  __shared__ float4 tile4[1024];

  const int wave = threadIdx.x >> 6;
  const int lane = threadIdx.x & 63;
  const int tid = threadIdx.x;
  const int p = blockIdx.x * 4 + wave;
  const int b = p >> 12;
  const int i = p & 4095;
  const float* xb = xyz + (size_t)b * (N_ * 3);

  const float qx = xb[3 * i];
  const float qy = xb[3 * i + 1];
  const float qz = xb[3 * i + 2];
  const float qxx =
      __fadd_rn(__fadd_rn(__fmul_rn(qx, qx), __fmul_rn(qy, qy)), __fmul_rn(qz, qz));
  const float nqxx = -qxx;

  unsigned long long pk[4] = {0ull, 0ull, 0ull, 0ull};
  for (int tile = 0; tile < 4; ++tile) {
    {
      const float4* gsrc = (const float4*)(xb + tile * 3072);
      float4 r0v = gsrc[tid * 3];
      float4 r1 = gsrc[tid * 3 + 1];
      float4 r2 = gsrc[tid * 3 + 2];
      const int base = tid * 4;
      tile4[base]     = make_float4(r0v.x, r0v.y, r0v.z, 0.0f);
      tile4[base + 1] = make_float4(r0v.w, r1.x, r1.y, 0.0f);
      tile4[base + 2] = make_float4(r1.z, r1.w, r2.x, 0.0f);
      tile4[base + 3] = make_float4(r2.y, r2.z, r2.w, 0.0f);
    }
    __syncthreads();
#pragma unroll 4
    for (int tloc = 0; tloc < 16; ++tloc) {
      const int j = tile * 1024 + tloc * 64 + lane;
      const float4 pt = tile4[tloc * 64 + lane];
      const unsigned long long key = knn_key(qx, qy, qz, nqxx, pt.x, pt.y, pt.z, j);
      const bool c0 = key > pk[0], c1 = key > pk[1], c2 = key > pk[2], c3 = key > pk[3];
      pk[3] = c3 ? (c2 ? pk[2] : key) : pk[3];
      pk[2] = c2 ? (c1 ? pk[1] : key) : pk[2];
      pk[1] = c1 ? (c0 ? pk[0] : key) : pk[1];
      pk[0] = c0 ? key : pk[0];
    }
    __syncthreads();
  }

  int nidx[K_];
  int h = 0;
#pragma unroll
  for (int k = 0; k < K_; ++k) {
    unsigned long long v = pk[0];
#pragma unroll
    for (int off = 32; off >= 1; off >>= 1) {
      unsigned long long ov = __shfl_xor(v, off, 64);
      if (ov > v) v = ov;
    }
    nidx[k] = (4095 - (int)(unsigned)(v & 0xFFFFFFFFull)) & (N_ - 1);
    if (pk[0] == v) {
      pk[0] = pk[1]; pk[1] = pk[2]; pk[2] = pk[3]; pk[3] = 0ull;
      ++h;
    }
  }
  if (__ballot(h >= 4) != 0ull) {
    unsigned long long q[K_];
#pragma unroll
    for (int k = 0; k < K_; ++k) q[k] = 0ull;
    for (int t = 0; t < 64; ++t) {
      const int j = t * 64 + lane;
      const unsigned long long key =
          knn_key(qx, qy, qz, nqxx, xb[3 * j], xb[3 * j + 1], xb[3 * j + 2], j);
      bool c[K_];
#pragma unroll
      for (int s = 0; s < K_; ++s) c[s] = key > q[s];
#pragma unroll
      for (int s = K_ - 1; s >= 1; --s)
        q[s] = c[s] ? (c[s - 1] ? q[s - 1] : key) : q[s];
      q[0] = c[0] ? key : q[0];
    }
#pragma unroll
    for (int k = 0; k < K_; ++k) {
      unsigned long long v = q[0];
#pragma unroll
      for (int off = 32; off >= 1; off >>= 1) {
        unsigned long long ov = __shfl_xor(v, off, 64);
        if (ov > v) v = ov;
      }
      nidx[k] = (4095 - (int)(unsigned)(v & 0xFFFFFFFFull)) & (N_ - 1);
      if (q[0] == v) {
#pragma unroll
        for (int s = 0; s < K_ - 1; ++s) q[s] = q[s + 1];
        q[K_ - 1] = 0ull;
      }
    }
  }

  float c00 = 0, c01 = 0, c02 = 0, c11 = 0, c12 = 0, c22 = 0;
  float mrx = 0, mry = 0, mrz = 0, md = 0;
#pragma unroll
  for (int k = 0; k < K_; ++k) {
    const int j = nidx[k];
    const float rx = __fsub_rn(xb[3 * j], qx);
    const float ry = __fsub_rn(xb[3 * j + 1], qy);
    const float rz = __fsub_rn(xb[3 * j + 2], qz);
    c00 = __fadd_rn(c00, __fmul_rn(rx, rx));
    c01 = __fadd_rn(c01, __fmul_rn(rx, ry));
    c02 = __fadd_rn(c02, __fmul_rn(rx, rz));
    c11 = __fadd_rn(c11, __fmul_rn(ry, ry));
    c12 = __fadd_rn(c12, __fmul_rn(ry, rz));
    c22 = __fadd_rn(c22, __fmul_rn(rz, rz));
    mrx = __fadd_rn(mrx, rx);
    mry = __fadd_rn(mry, ry);
    mrz = __fadd_rn(mrz, rz);
    const float nn = __fadd_rn(__fadd_rn(__fmul_rn(rx, rx), __fmul_rn(ry, ry)),
                               __fmul_rn(rz, rz));
    md = __fadd_rn(md, sqrtf(nn));
  }
  const float s16 = 0.0625f;
  float Z[3][3];
  eig3_f(__fmul_rn(c00, s16), __fmul_rn(c01, s16), __fmul_rn(c02, s16),
         __fmul_rn(c11, s16), __fmul_rn(c12, s16), __fmul_rn(c22, s16), Z);
  float gf[10];
  gf[0] = Z[0][0]; gf[1] = Z[1][0]; gf[2] = Z[2][0];
  gf[3] = Z[0][2]; gf[4] = Z[1][2]; gf[5] = Z[2][2];
  gf[6] = __fmul_rn(mrx, s16); gf[7] = __fmul_rn(mry, s16);
  gf[8] = __fmul_rn(mrz, s16);
  gf[9] = __fmul_rn(md, s16);

  float acc = 0.0f;
#pragma unroll
  for (int ii = 0; ii < 10; ++ii) acc += gf[ii] * geo_w1[ii * 64 + lane];
  acc += geo_b1[lane];
  float yr;
  {
    float m = wave_sum64(acc) * (1.0f / 64.0f);
    float xm = acc - m;
    float var = wave_sum64(xm * xm) * (1.0f / 64.0f);
    float yv = xm * (1.0f / sqrtf(var + 1e-5f)) * geo_g1[lane] + geo_be1[lane];
    yr = fmaxf(yv, 0.0f);
  }
  float ge = 0.0f;
#pragma unroll 8
  for (int jj = 0; jj < 64; ++jj) ge += __shfl(yr, jj, 64) * geo_w2[jj * 64 + lane];
  ge += geo_b2[lane];

  const float* fb = feats + (size_t)b * N_ * C_;
  const float* fi = fb + (size_t)i * C_;
  const float f0 = fi[lane];
  const float f1 = fi[64 + lane];
  float s0 = 0.0f, s1 = 0.0f;
#pragma unroll
  for (int k = 0; k < K_; ++k) {
    const float* fj = fb + (size_t)nidx[k] * C_;
    s0 += fabsf(f0 - fj[lane]);
    s1 += fabsf(f1 - fj[64 + lane]);
  }
  s0 *= (1.0f / 16.0f);
  s1 *= (1.0f / 16.0f);
  float acc2 = 0.0f;
#pragma unroll 8
  for (int c = 0; c < 64; ++c) acc2 += __shfl(s0, c, 64) * diff_w1[c * 64 + lane];
#pragma unroll 8
  for (int c = 64; c < 128; ++c) acc2 += __shfl(s1, c - 64, 64) * diff_w1[c * 64 + lane];
  acc2 += diff_b1[lane];
  float yr2;
  {
    float m = wave_sum64(acc2) * (1.0f / 64.0f);
    float xm = acc2 - m;
    float var = wave_sum64(xm * xm) * (1.0f / 64.0f);
    float yv = xm * (1.0f / sqrtf(var + 1e-5f)) * diff_g1[lane] + diff_be1[lane];
    yr2 = fmaxf(yv, 0.0f);
  }
  float de = 0.0f;
#pragma unroll 8
  for (int jj = 0; jj < 64; ++jj) de += __shfl(yr2, jj, 64) * diff_w2[jj * 64 + lane];
  de += diff_b2[lane];

  {
    const int u = lane & 31;
    float a = 0.0f;
#pragma unroll 8
    for (int c = 0; c < 64; ++c) a += __shfl(ge, c, 64) * ep_w1[c * 32 + u];
#pragma unroll 8
    for (int c = 64; c < 128; ++c) a += __shfl(de, c - 64, 64) * ep_w1[c * 32 + u];
    a += ep_b1[u];
    float hh = (lane < 32) ? fmaxf(a, 0.0f) * ep_w2[u] : 0.0f;
    float tsum = wave_sum64(hh) + ep_b2[0];
    float prob = 1.0f / (1.0f + expf(-tsum));

    const float gep = ge * prob;
    const float dep = de * prob;
    float a0 = 0.0f, a1 = 0.0f;
#pragma unroll 4
    for (int c = 0; c < 64; ++c) {
      float ec = __shfl(f0, c, 64);
      a0 += ec * ref_w1[c * 128 + lane];
      a1 += ec * ref_w1[c * 128 + 64 + lane];
    }
#pragma unroll 4
    for (int c = 64; c < 128; ++c) {
      float ec = __shfl(f1, c - 64, 64);
      a0 += ec * ref_w1[c * 128 + lane];
      a1 += ec * ref_w1[c * 128 + 64 + lane];
    }
#pragma unroll 4
    for (int c = 128; c < 192; ++c) {
      float ec = __shfl(gep, c - 128, 64);
      a0 += ec * ref_w1[c * 128 + lane];
      a1 += ec * ref_w1[c * 128 + 64 + lane];
    }
#pragma unroll 4
    for (int c = 192; c < 256; ++c) {
      float ec = __shfl(dep, c - 192, 64);
      a0 += ec * ref_w1[c * 128 + lane];
      a1 += ec * ref_w1[c * 128 + 64 + lane];
    }
    a0 += ref_b1[lane];
    a1 += ref_b1[64 + lane];
    float mm2 = wave_sum64(a0 + a1) * (1.0f / 128.0f);
    float d0 = a0 - mm2, d1 = a1 - mm2;
    float var2 = wave_sum64(d0 * d0 + d1 * d1) * (1.0f / 128.0f);
    float rs = 1.0f / sqrtf(var2 + 1e-5f);
    float y0 = d0 * rs * ref_g1[lane] + ref_be1[lane];
    float y1 = d1 * rs * ref_g1[64 + lane] + ref_be1[64 + lane];
    y0 = fmaxf(y0, 0.0f) + f0;
    y1 = fmaxf(y1, 0.0f) + f1;
    out[(size_t)p * 128 + lane] = y0;
    out[(size_t)p * 128 + 64 + lane] = y1;
    if (lane == 0) out_prob[p] = prob;
  }
}

extern "C" void kernel_launch(void* const* d_in, const int* in_sizes, int n_in,
                              void* d_out, int out_size, void* d_ws, size_t ws_size,
                              hipStream_t stream) {
  const float* xyz = (const float*)d_in[0];
  const float* features = (const float*)d_in[1];
  const float* geo_w1 = (const float*)d_in[2];
  const float* geo_b1 = (const float*)d_in[3];
  const float* geo_g1 = (const float*)d_in[4];
  const float* geo_be1 = (const float*)d_in[5];
  const float* geo_w2 = (const float*)d_in[6];
  const float* geo_b2 = (const float*)d_in[7];
  const float* diff_w1 = (const float*)d_in[8];
  const float* diff_b1 = (const float*)d_in[9];
  const float* diff_g1 = (const float*)d_in[10];
  const float* diff_be1 = (const float*)d_in[11];
  const float* diff_w2 = (const float*)d_in[12];
  const float* diff_b2 = (const float*)d_in[13];
  const float* ep_w1 = (const float*)d_in[14];
  const float* ep_b1 = (const float*)d_in[15];
  const float* ep_w2 = (const float*)d_in[16];
  const float* ep_b2 = (const float*)d_in[17];
  const float* ref_w1 = (const float*)d_in[18];
  const float* ref_b1 = (const float*)d_in[19];
  const float* ref_g1 = (const float*)d_in[20];
  const float* ref_be1 = (const float*)d_in[21];

  float* out = (float*)d_out;
  float* out_prob = out + (size_t)NPT * C_;

  if (ws_size >= (size_t)(2 * 1024 * 1024)) {
    int* nidx_ws = (int*)d_ws;                             // 1 MB
    float* gf_ws = (float*)((char*)d_ws + (1u << 20));     // 768 KB
    knn_kernel<<<dim3(NPT / 8), dim3(256), 0, stream>>>(xyz, nidx_ws);
    eig_kernel<<<dim3(NPT / 64), dim3(64), 0, stream>>>(xyz, nidx_ws, gf_ws);
    mlp_kernel<<<dim3(NPT / 16), dim3(256), 0, stream>>>(
        features, nidx_ws, gf_ws, geo_w1, geo_b1, geo_g1, geo_be1, geo_w2,
        geo_b2, diff_w1, diff_b1, diff_g1, diff_be1, diff_w2, diff_b2, ep_w1,
        ep_b1, ep_w2, ep_b2, ref_w1, ref_b1, ref_g1, ref_be1, out, out_prob);
  } else {
    fused_kernel<<<dim3(NPT / 4), dim3(256), 0, stream>>>(
        xyz, features, geo_w1, geo_b1, geo_g1, geo_be1, geo_w2, geo_b2,
        diff_w1, diff_b1, diff_g1, diff_be1, diff_w2, diff_b2, ep_w1, ep_b1,
        ep_w2, ep_b2, ref_w1, ref_b1, ref_g1, ref_be1, out, out_prob);
  }
}